// Round 6
// baseline (473.179 us; speedup 1.0000x reference)
//
#include <hip/hip_runtime.h>
#include <math.h>

#define BATCH 2
#define SEQ   2048
#define DM    1024
#define NH    16
#define HD    64
#define MTOT  (BATCH*SEQ)            // 4096

typedef short v8s __attribute__((ext_vector_type(8)));   // 8 bf16 = 4 VGPR
typedef float v4f __attribute__((ext_vector_type(4)));

#define MFMA16(a, b, c) __builtin_amdgcn_mfma_f32_16x16x32_bf16((a), (b), (c), 0, 0, 0)

__device__ __forceinline__ short f2b(float f) {          // fp32 -> bf16 bits, RNE
    union { float f; unsigned u; } v; v.f = f;
    unsigned r = (v.u + 0x7FFFu + ((v.u >> 16) & 1u)) >> 16;
    return (short)r;
}

// ---------------------------------------------------------------------------
// Kernel 0: fp32 -> bf16-bits elementwise convert (8 elems / thread).
// ---------------------------------------------------------------------------
__global__ __launch_bounds__(256) void cvt_kernel(
    const float* __restrict__ src, short* __restrict__ dst, int n8)
{
    int i = blockIdx.x * 256 + threadIdx.x;
    if (i >= n8) return;
    const float4* s4 = (const float4*)src;
    float4 a = s4[2 * i], b = s4[2 * i + 1];
    v8s p;
    p[0] = f2b(a.x); p[1] = f2b(a.y); p[2] = f2b(a.z); p[3] = f2b(a.w);
    p[4] = f2b(b.x); p[5] = f2b(b.y); p[6] = f2b(b.z); p[7] = f2b(b.w);
    *(v8s*)&dst[8 * i] = p;
}

// ---------------------------------------------------------------------------
// Kernel 1: K/V projections via MFMA + register prefetch.
//   z=0: K = RoPE(x @ Wk^T) -> [bh][key][d]
//   z=1: V = x @ Wv^T stored transposed -> Vt[bh][d][key]
// grid = (MTOT/64, NH, 2), 256 thr.
// ---------------------------------------------------------------------------
__global__ __launch_bounds__(256) void kv_rope_mfma(
    const short* __restrict__ xb, const short* __restrict__ Wkb,
    const short* __restrict__ Wvb, short* __restrict__ K, short* __restrict__ Vt)
{
    const int zz = blockIdx.z;
    const short* __restrict__ Wb = zz ? Wvb : Wkb;
    const int m0 = blockIdx.x * 64, h = blockIdx.y, e0 = h * 64;
    const int tid = threadIdx.x;
    const int w = tid >> 6, lane = tid & 63, lq = lane >> 4, lr = lane & 15;
    const int sr = tid >> 2, sc = (tid & 3) * 8;

    __shared__ short As[64][32];
    __shared__ short Bs[64][32];
    __shared__ float Cs[64][65];

    v4f acc[4];
    #pragma unroll
    for (int nt = 0; nt < 4; ++nt)
        for (int r = 0; r < 4; ++r) acc[nt][r] = 0.f;

    v8s av = *(const v8s*)&xb[(size_t)(m0 + sr) * DM + sc];
    v8s bv = *(const v8s*)&Wb[(size_t)(e0 + sr) * DM + sc];
    for (int k0 = 0; k0 < DM; k0 += 32) {
        __syncthreads();
        *(v8s*)&As[sr][sc] = av;
        *(v8s*)&Bs[sr][sc] = bv;
        __syncthreads();
        if (k0 + 32 < DM) {                       // prefetch next k-slab
            av = *(const v8s*)&xb[(size_t)(m0 + sr) * DM + k0 + 32 + sc];
            bv = *(const v8s*)&Wb[(size_t)(e0 + sr) * DM + k0 + 32 + sc];
        }
        v8s a = *(const v8s*)&As[16 * w + lr][lq * 8];
        #pragma unroll
        for (int nt = 0; nt < 4; ++nt) {
            v8s b = *(const v8s*)&Bs[16 * nt + lr][lq * 8];
            acc[nt] = MFMA16(a, b, acc[nt]);
        }
    }

    #pragma unroll
    for (int nt = 0; nt < 4; ++nt)
        #pragma unroll
        for (int r = 0; r < 4; ++r)
            Cs[16 * w + lq * 4 + r][16 * nt + lr] = acc[nt][r];
    __syncthreads();

    const int b = m0 >> 11, n0 = m0 & (SEQ - 1);
    const int bh = b * NH + h;
    const float LN1E4_D32 = 0.28782313662425572f;   // ln(10000)/32

    if (zz == 0) {
        int mm = tid >> 2, d0 = (tid & 3) * 16;
        int n = n0 + mm;
        v8s o1, o2;
        #pragma unroll
        for (int i = 0; i < 16; ++i) {
            int j = d0 + i, jj = j & 31;
            float inv_freq = expf(-(float)jj * LN1E4_D32);
            float ang = (float)n * inv_freq;
            float c, s;
            sincosf(ang, &s, &c);
            float v = Cs[mm][j];
            float rot = (j < 32) ? -Cs[mm][j + 32] : Cs[mm][j - 32];
            short bb = f2b(v * c + rot * s);
            if (i < 8) o1[i] = bb; else o2[i - 8] = bb;
        }
        size_t base = ((size_t)bh * SEQ + n) * HD + d0;
        *(v8s*)&K[base] = o1;
        *(v8s*)&K[base + 8] = o2;
    } else {
        int d = tid >> 2, ks0 = (tid & 3) * 16;
        v8s o1, o2;
        #pragma unroll
        for (int i = 0; i < 8; ++i) {
            o1[i] = f2b(Cs[ks0 + i][d]);
            o2[i] = f2b(Cs[ks0 + 8 + i][d]);
        }
        size_t base = ((size_t)bh * HD + d) * SEQ + n0 + ks0;
        *(v8s*)&Vt[base] = o1;
        *(v8s*)&Vt[base + 8] = o2;
    }
}

// ---------------------------------------------------------------------------
// Kernel 2: fused Q-proj + RoPE + flash attention, all MFMA.
//  - register prefetch of next K/V chunk (loads in flight across compute)
//  - exp2-domain online softmax, additive -1e30 mask bias
//  - Q A-fragments in registers (wave-private)
// grid = (MTOT/64, NH), 256 threads / 4 waves.
// ---------------------------------------------------------------------------
__global__ __launch_bounds__(256) void attn_mfma(
    const short* __restrict__ xb, const short* __restrict__ Wqb,
    const short* __restrict__ K, const short* __restrict__ Vt,
    const int* __restrict__ mask, short* __restrict__ O)
{
    const int m0 = blockIdx.x * 64, h = blockIdx.y, e0 = h * 64;
    const int b = m0 >> 11, n0 = m0 & (SEQ - 1), bh = b * NH + h;
    const int tid = threadIdx.x;
    const int w = tid >> 6, lane = tid & 63, lq = lane >> 4, lr = lane & 15;
    const int sr = tid >> 2, sc = (tid & 3) * 8;

    __shared__ union {
        struct { short As[64][32]; short Bs[64][32]; float Cs[64][65]; } p1;
        struct { short Ks[64][72]; short Vs[64][72]; short Ps[64][72]; } p2;
    } u;
    __shared__ float mbias[64];

    // ---- Phase 1: Q-tile = x_tile @ Wq_h^T (register-prefetched k-loop) ----
    v4f acc[4];
    #pragma unroll
    for (int nt = 0; nt < 4; ++nt)
        for (int r = 0; r < 4; ++r) acc[nt][r] = 0.f;

    v8s av = *(const v8s*)&xb[(size_t)(m0 + sr) * DM + sc];
    v8s bv = *(const v8s*)&Wqb[(size_t)(e0 + sr) * DM + sc];
    for (int k0 = 0; k0 < DM; k0 += 32) {
        __syncthreads();
        *(v8s*)&u.p1.As[sr][sc] = av;
        *(v8s*)&u.p1.Bs[sr][sc] = bv;
        __syncthreads();
        if (k0 + 32 < DM) {
            av = *(const v8s*)&xb[(size_t)(m0 + sr) * DM + k0 + 32 + sc];
            bv = *(const v8s*)&Wqb[(size_t)(e0 + sr) * DM + k0 + 32 + sc];
        }
        v8s a = *(const v8s*)&u.p1.As[16 * w + lr][lq * 8];
        #pragma unroll
        for (int nt = 0; nt < 4; ++nt) {
            v8s bb = *(const v8s*)&u.p1.Bs[16 * nt + lr][lq * 8];
            acc[nt] = MFMA16(a, bb, acc[nt]);
        }
    }
    #pragma unroll
    for (int nt = 0; nt < 4; ++nt)
        #pragma unroll
        for (int r = 0; r < 4; ++r)
            u.p1.Cs[16 * w + lq * 4 + r][16 * nt + lr] = acc[nt][r];
    __syncthreads();

    // ---- RoPE into registers; scale = 1/8 * log2(e) (exp2-domain) ----
    v8s q1, q2;
    {
        const float LN1E4_D32 = 0.28782313662425572f;
        const float QSCALE = 0.18033688011112042f;       // 0.125 * log2(e)
        int mm = tid >> 2, d0 = (tid & 3) * 16;
        int n = n0 + mm;
        #pragma unroll
        for (int i = 0; i < 16; ++i) {
            int j = d0 + i, jj = j & 31;
            float inv_freq = expf(-(float)jj * LN1E4_D32);
            float ang = (float)n * inv_freq;
            float c, s;
            sincosf(ang, &s, &c);
            float v = u.p1.Cs[mm][j];
            float rot = (j < 32) ? -u.p1.Cs[mm][j + 32] : u.p1.Cs[mm][j - 32];
            short bb = f2b(QSCALE * (v * c + rot * s));
            if (i < 8) q1[i] = bb; else q2[i - 8] = bb;
        }
    }
    __syncthreads();                      // all Cs reads done (Ps aliases Cs)
    {
        int mm = tid >> 2, d0 = (tid & 3) * 16;
        *(v8s*)&u.p2.Ps[mm][d0] = q1;
        *(v8s*)&u.p2.Ps[mm][d0 + 8] = q2;
    }
    __syncthreads();
    v8s aq0 = *(const v8s*)&u.p2.Ps[16 * w + lr][lq * 8];       // wave-private
    v8s aq1 = *(const v8s*)&u.p2.Ps[16 * w + lr][32 + lq * 8];

    // ---- Phase 2: flash loop with register-prefetched K/V chunks ----
    float mrun[4], lrun[4];
    #pragma unroll
    for (int r = 0; r < 4; ++r) { mrun[r] = -1e30f; lrun[r] = 0.f; }
    v4f o[4];
    #pragma unroll
    for (int nt = 0; nt < 4; ++nt)
        for (int r = 0; r < 4; ++r) o[nt][r] = 0.f;

    const int r2 = tid >> 2, cc = (tid & 3) * 16;
    const short* __restrict__ Kb = K + (size_t)bh * SEQ * HD;
    const short* __restrict__ Vb = Vt + (size_t)bh * HD * SEQ;

    v8s k1 = *(const v8s*)&Kb[(size_t)r2 * HD + cc];
    v8s k2 = *(const v8s*)&Kb[(size_t)r2 * HD + cc + 8];
    v8s v1 = *(const v8s*)&Vb[(size_t)r2 * SEQ + cc];
    v8s v2 = *(const v8s*)&Vb[(size_t)r2 * SEQ + cc + 8];

    for (int c0 = 0; c0 < SEQ; c0 += 64) {
        __syncthreads();                              // prev chunk LDS reads done
        *(v8s*)&u.p2.Ks[r2][cc] = k1;
        *(v8s*)&u.p2.Ks[r2][cc + 8] = k2;
        *(v8s*)&u.p2.Vs[r2][cc] = v1;
        *(v8s*)&u.p2.Vs[r2][cc + 8] = v2;
        if (tid < 64) mbias[tid] = mask[b * SEQ + c0 + tid] ? 0.f : -1e30f;
        __syncthreads();
        if (c0 + 64 < SEQ) {                          // prefetch next chunk
            k1 = *(const v8s*)&Kb[(size_t)(c0 + 64 + r2) * HD + cc];
            k2 = *(const v8s*)&Kb[(size_t)(c0 + 64 + r2) * HD + cc + 8];
            v1 = *(const v8s*)&Vb[(size_t)r2 * SEQ + c0 + 64 + cc];
            v2 = *(const v8s*)&Vb[(size_t)r2 * SEQ + c0 + 64 + cc + 8];
        }

        // S = Q @ K^T  (log2-domain scale pre-folded into Q)
        v4f s[4];
        #pragma unroll
        for (int nt = 0; nt < 4; ++nt)
            for (int r = 0; r < 4; ++r) s[nt][r] = 0.f;
        #pragma unroll
        for (int ks = 0; ks < 2; ++ks) {
            v8s a = ks ? aq1 : aq0;
            #pragma unroll
            for (int nt = 0; nt < 4; ++nt) {
                v8s bb = *(const v8s*)&u.p2.Ks[16 * nt + lr][ks * 32 + lq * 8];
                s[nt] = MFMA16(a, bb, s[nt]);
            }
        }
        // additive mask bias (masked keys -> -1e30 -> p underflows to 0)
        #pragma unroll
        for (int nt = 0; nt < 4; ++nt) {
            float bias = mbias[16 * nt + lr];
            #pragma unroll
            for (int r = 0; r < 4; ++r) s[nt][r] += bias;
        }
        // online softmax (exp2 domain), butterfly over 16-lane col group
        float alpha[4];
        #pragma unroll
        for (int r = 0; r < 4; ++r) {
            float mc = fmaxf(fmaxf(s[0][r], s[1][r]), fmaxf(s[2][r], s[3][r]));
            mc = fmaxf(mc, __shfl_xor(mc, 1));
            mc = fmaxf(mc, __shfl_xor(mc, 2));
            mc = fmaxf(mc, __shfl_xor(mc, 4));
            mc = fmaxf(mc, __shfl_xor(mc, 8));
            float mnew = fmaxf(mrun[r], mc);
            alpha[r] = exp2f(mrun[r] - mnew);
            mrun[r] = mnew;
        }
        float rs[4] = {0.f, 0.f, 0.f, 0.f};
        #pragma unroll
        for (int nt = 0; nt < 4; ++nt) {
            #pragma unroll
            for (int r = 0; r < 4; ++r) {
                float p = exp2f(s[nt][r] - mrun[r]);
                rs[r] += p;
                u.p2.Ps[16 * w + lq * 4 + r][16 * nt + lr] = f2b(p);
            }
        }
        #pragma unroll
        for (int r = 0; r < 4; ++r) {
            rs[r] += __shfl_xor(rs[r], 1);
            rs[r] += __shfl_xor(rs[r], 2);
            rs[r] += __shfl_xor(rs[r], 4);
            rs[r] += __shfl_xor(rs[r], 8);
            lrun[r] = lrun[r] * alpha[r] + rs[r];
        }
        #pragma unroll
        for (int nt = 0; nt < 4; ++nt)
            #pragma unroll
            for (int r = 0; r < 4; ++r) o[nt][r] *= alpha[r];

        // O += P @ V  (Ps row-strip is wave-private: no barrier needed)
        #pragma unroll
        for (int ks = 0; ks < 2; ++ks) {
            v8s a = *(const v8s*)&u.p2.Ps[16 * w + lr][ks * 32 + lq * 8];
            #pragma unroll
            for (int nt = 0; nt < 4; ++nt) {
                v8s bb = *(const v8s*)&u.p2.Vs[16 * nt + lr][ks * 32 + lq * 8];
                o[nt] = MFMA16(a, bb, o[nt]);
            }
        }
    }

    // ---- finalize (all-masked rows -> 0 via mrun guard) ----
    #pragma unroll
    for (int r = 0; r < 4; ++r) {
        float inv = (mrun[r] > -1e29f && lrun[r] > 0.f) ? 1.f / lrun[r] : 0.f;
        int qrow = 16 * w + lq * 4 + r;
        #pragma unroll
        for (int nt = 0; nt < 4; ++nt)
            O[(size_t)(m0 + qrow) * DM + h * HD + 16 * nt + lr] =
                f2b(o[nt][r] * inv);
    }
}

// ---------------------------------------------------------------------------
// Kernel 3: out = O @ Wo^T via MFMA + register prefetch, fp32 store.
// grid = (MTOT/64, DM/64).
// ---------------------------------------------------------------------------
__global__ __launch_bounds__(256) void oproj_mfma(
    const short* __restrict__ O, const short* __restrict__ Wob,
    float* __restrict__ out)
{
    const int m0 = blockIdx.x * 64, e0 = blockIdx.y * 64;
    const int tid = threadIdx.x;
    const int w = tid >> 6, lane = tid & 63, lq = lane >> 4, lr = lane & 15;
    const int sr = tid >> 2, sc = (tid & 3) * 8;

    __shared__ short As[64][32];
    __shared__ short Bs[64][32];

    v4f acc[4];
    #pragma unroll
    for (int nt = 0; nt < 4; ++nt)
        for (int r = 0; r < 4; ++r) acc[nt][r] = 0.f;

    v8s av = *(const v8s*)&O[(size_t)(m0 + sr) * DM + sc];
    v8s bv = *(const v8s*)&Wob[(size_t)(e0 + sr) * DM + sc];
    for (int k0 = 0; k0 < DM; k0 += 32) {
        __syncthreads();
        *(v8s*)&As[sr][sc] = av;
        *(v8s*)&Bs[sr][sc] = bv;
        __syncthreads();
        if (k0 + 32 < DM) {
            av = *(const v8s*)&O[(size_t)(m0 + sr) * DM + k0 + 32 + sc];
            bv = *(const v8s*)&Wob[(size_t)(e0 + sr) * DM + k0 + 32 + sc];
        }
        v8s a = *(const v8s*)&As[16 * w + lr][lq * 8];
        #pragma unroll
        for (int nt = 0; nt < 4; ++nt) {
            v8s bb = *(const v8s*)&Bs[16 * nt + lr][lq * 8];
            acc[nt] = MFMA16(a, bb, acc[nt]);
        }
    }

    #pragma unroll
    for (int r = 0; r < 4; ++r) {
        int m = m0 + 16 * w + lq * 4 + r;
        #pragma unroll
        for (int nt = 0; nt < 4; ++nt)
            out[(size_t)m * DM + e0 + 16 * nt + lr] = acc[nt][r];
    }
}

// ---------------------------------------------------------------------------
extern "C" void kernel_launch(void* const* d_in, const int* in_sizes, int n_in,
                              void* d_out, int out_size, void* d_ws, size_t ws_size,
                              hipStream_t stream)
{
    const float* x    = (const float*)d_in[0];
    const int*   mask = (const int*)d_in[1];
    const float* Wq   = (const float*)d_in[2];
    const float* Wk   = (const float*)d_in[3];
    const float* Wv   = (const float*)d_in[4];
    const float* Wo   = (const float*)d_in[5];
    float* out = (float*)d_out;

    // ws (24 MiB of shorts): xb | Wqb | Wkb | Wvb | Wob | O
    short* xb  = (short*)d_ws;                    // 4 Mi
    short* Wqb = xb  + (size_t)MTOT * DM;         // 1 Mi each
    short* Wkb = Wqb + (size_t)DM * DM;
    short* Wvb = Wkb + (size_t)DM * DM;
    short* Wob = Wvb + (size_t)DM * DM;
    short* O   = Wob + (size_t)DM * DM;           // 4 Mi
    // d_out (16 MiB) doubles as K/Vt scratch until the final projection
    short* K  = (short*)d_out;                    // 4 Mi
    short* Vt = K + (size_t)MTOT * DM;            // 4 Mi

    const int NX8 = MTOT * DM / 8, NW8 = DM * DM / 8;
    cvt_kernel<<<(NX8 + 255) / 256, 256, 0, stream>>>(x, xb, NX8);
    cvt_kernel<<<(NW8 + 255) / 256, 256, 0, stream>>>(Wq, Wqb, NW8);
    cvt_kernel<<<(NW8 + 255) / 256, 256, 0, stream>>>(Wk, Wkb, NW8);
    cvt_kernel<<<(NW8 + 255) / 256, 256, 0, stream>>>(Wv, Wvb, NW8);
    cvt_kernel<<<(NW8 + 255) / 256, 256, 0, stream>>>(Wo, Wob, NW8);

    dim3 g1(MTOT / 64, NH, 2);
    kv_rope_mfma<<<g1, 256, 0, stream>>>(xb, Wkb, Wvb, K, Vt);

    dim3 g2(MTOT / 64, NH);
    attn_mfma<<<g2, 256, 0, stream>>>(xb, Wqb, K, Vt, mask, O);

    dim3 g3(MTOT / 64, DM / 64);
    oproj_mfma<<<g3, 256, 0, stream>>>(O, Wob, out);
}

// Round 7
// 320.235 us; speedup vs baseline: 1.4776x; 1.4776x over previous
//
#include <hip/hip_runtime.h>
#include <math.h>

#define BATCH 2
#define SEQ   2048
#define DM    1024
#define NH    16
#define HD    64
#define MTOT  (BATCH*SEQ)            // 4096

typedef short v8s __attribute__((ext_vector_type(8)));   // 8 bf16 = 4 VGPR
typedef float v4f __attribute__((ext_vector_type(4)));

#define MFMA16(a, b, c) __builtin_amdgcn_mfma_f32_16x16x32_bf16((a), (b), (c), 0, 0, 0)

__device__ __forceinline__ short f2b(float f) {          // fp32 -> bf16 bits, RNE
    union { float f; unsigned u; } v; v.f = f;
    unsigned r = (v.u + 0x7FFFu + ((v.u >> 16) & 1u)) >> 16;
    return (short)r;
}

// ---------------------------------------------------------------------------
// Kernel 0: fp32 -> bf16-bits elementwise convert (8 elems / thread).
// ---------------------------------------------------------------------------
__global__ __launch_bounds__(256) void cvt_kernel(
    const float* __restrict__ src, short* __restrict__ dst, int n8)
{
    int i = blockIdx.x * 256 + threadIdx.x;
    if (i >= n8) return;
    const float4* s4 = (const float4*)src;
    float4 a = s4[2 * i], b = s4[2 * i + 1];
    v8s p;
    p[0] = f2b(a.x); p[1] = f2b(a.y); p[2] = f2b(a.z); p[3] = f2b(a.w);
    p[4] = f2b(b.x); p[5] = f2b(b.y); p[6] = f2b(b.z); p[7] = f2b(b.w);
    *(v8s*)&dst[8 * i] = p;
}

// ---------------------------------------------------------------------------
// Kernel 1: K/V projections via MFMA (exact R5 structure — no manual prefetch).
//   z=0: K = RoPE(x @ Wk^T) -> [bh][key][d]
//   z=1: V = x @ Wv^T stored transposed -> Vt[bh][d][key]
// grid = (MTOT/64, NH, 2), 256 thr.
// ---------------------------------------------------------------------------
__global__ __launch_bounds__(256) void kv_rope_mfma(
    const short* __restrict__ xb, const short* __restrict__ Wkb,
    const short* __restrict__ Wvb, short* __restrict__ K, short* __restrict__ Vt)
{
    const int zz = blockIdx.z;
    const short* __restrict__ Wb = zz ? Wvb : Wkb;
    const int m0 = blockIdx.x * 64, h = blockIdx.y, e0 = h * 64;
    const int tid = threadIdx.x;
    const int w = tid >> 6, lane = tid & 63, lq = lane >> 4, lr = lane & 15;
    const int sr = tid >> 2, sc = (tid & 3) * 8;

    __shared__ short As[64][32];
    __shared__ short Bs[64][32];
    __shared__ float Cs[64][65];

    v4f acc[4];
    #pragma unroll
    for (int nt = 0; nt < 4; ++nt)
        for (int r = 0; r < 4; ++r) acc[nt][r] = 0.f;

    for (int k0 = 0; k0 < DM; k0 += 32) {
        v8s av = *(const v8s*)&xb[(size_t)(m0 + sr) * DM + k0 + sc];
        v8s bv = *(const v8s*)&Wb[(size_t)(e0 + sr) * DM + k0 + sc];
        __syncthreads();
        *(v8s*)&As[sr][sc] = av;
        *(v8s*)&Bs[sr][sc] = bv;
        __syncthreads();
        v8s a = *(const v8s*)&As[16 * w + lr][lq * 8];
        #pragma unroll
        for (int nt = 0; nt < 4; ++nt) {
            v8s b = *(const v8s*)&Bs[16 * nt + lr][lq * 8];
            acc[nt] = MFMA16(a, b, acc[nt]);
        }
    }

    #pragma unroll
    for (int nt = 0; nt < 4; ++nt)
        #pragma unroll
        for (int r = 0; r < 4; ++r)
            Cs[16 * w + lq * 4 + r][16 * nt + lr] = acc[nt][r];
    __syncthreads();

    const int b = m0 >> 11, n0 = m0 & (SEQ - 1);
    const int bh = b * NH + h;
    const float LN1E4_D32 = 0.28782313662425572f;   // ln(10000)/32

    if (zz == 0) {
        int mm = tid >> 2, d0 = (tid & 3) * 16;
        int n = n0 + mm;
        v8s o1, o2;
        #pragma unroll
        for (int i = 0; i < 16; ++i) {
            int j = d0 + i, jj = j & 31;
            float inv_freq = expf(-(float)jj * LN1E4_D32);
            float ang = (float)n * inv_freq;
            float c, s;
            sincosf(ang, &s, &c);
            float v = Cs[mm][j];
            float rot = (j < 32) ? -Cs[mm][j + 32] : Cs[mm][j - 32];
            short bb = f2b(v * c + rot * s);
            if (i < 8) o1[i] = bb; else o2[i - 8] = bb;
        }
        size_t base = ((size_t)bh * SEQ + n) * HD + d0;
        *(v8s*)&K[base] = o1;
        *(v8s*)&K[base + 8] = o2;
    } else {
        int d = tid >> 2, ks0 = (tid & 3) * 16;
        v8s o1, o2;
        #pragma unroll
        for (int i = 0; i < 8; ++i) {
            o1[i] = f2b(Cs[ks0 + i][d]);
            o2[i] = f2b(Cs[ks0 + 8 + i][d]);
        }
        size_t base = ((size_t)bh * HD + d) * SEQ + n0 + ks0;
        *(v8s*)&Vt[base] = o1;
        *(v8s*)&Vt[base + 8] = o2;
    }
}

// ---------------------------------------------------------------------------
// Kernel 2: fused Q-proj + RoPE + flash attention, 128-row Q-tile per block.
// Wave w owns q-strips 16w.. and 64+16w.. (2 strips). RoPE done in-register
// (C-layout holds j and j^32 in nt and nt^2). Q staged once through Ps and
// held as register A/B-fragments. exp2-domain online softmax, -1e30 mask bias.
// R5-style inline staging (no manual prefetch). grid = (MTOT/128, NH).
// ---------------------------------------------------------------------------
__global__ __launch_bounds__(256) void attn_mfma(
    const short* __restrict__ xb, const short* __restrict__ Wqb,
    const short* __restrict__ K, const short* __restrict__ Vt,
    const int* __restrict__ mask, short* __restrict__ O)
{
    const int m0 = blockIdx.x * 128, h = blockIdx.y, e0 = h * 64;
    const int b = m0 >> 11, n0 = m0 & (SEQ - 1), bh = b * NH + h;
    const int tid = threadIdx.x;
    const int w = tid >> 6, lane = tid & 63, lq = lane >> 4, lr = lane & 15;
    const int sr = tid >> 2, sc = (tid & 3) * 8;

    __shared__ union {
        struct { short As[128][32]; short Bs[64][32]; } p1;   // 12 KB
        struct { short Ks[64][72]; short Vs[64][72]; } p2;    // 18.4 KB
    } u;
    __shared__ short Ps[128][72];                             // 18.4 KB
    __shared__ float mbias[64];

    // ---- Phase 1: Q[128][64] = x_tile @ Wq_h^T ----
    v4f acc[2][4];
    #pragma unroll
    for (int s = 0; s < 2; ++s)
        for (int nt = 0; nt < 4; ++nt)
            for (int r = 0; r < 4; ++r) acc[s][nt][r] = 0.f;

    for (int k0 = 0; k0 < DM; k0 += 32) {
        v8s a0 = *(const v8s*)&xb[(size_t)(m0 + sr) * DM + k0 + sc];
        v8s a1 = *(const v8s*)&xb[(size_t)(m0 + 64 + sr) * DM + k0 + sc];
        v8s bv = *(const v8s*)&Wqb[(size_t)(e0 + sr) * DM + k0 + sc];
        __syncthreads();
        *(v8s*)&u.p1.As[sr][sc] = a0;
        *(v8s*)&u.p1.As[64 + sr][sc] = a1;
        *(v8s*)&u.p1.Bs[sr][sc] = bv;
        __syncthreads();
        v8s aw0 = *(const v8s*)&u.p1.As[16 * w + lr][lq * 8];
        v8s aw1 = *(const v8s*)&u.p1.As[64 + 16 * w + lr][lq * 8];
        #pragma unroll
        for (int nt = 0; nt < 4; ++nt) {
            v8s bb = *(const v8s*)&u.p1.Bs[16 * nt + lr][lq * 8];
            acc[0][nt] = MFMA16(aw0, bb, acc[0][nt]);
            acc[1][nt] = MFMA16(aw1, bb, acc[1][nt]);
        }
    }

    // ---- RoPE in registers (pair nt <-> nt^2 is j <-> j^32), fold scale ----
    {
        const float LN1E4_D32 = 0.28782313662425572f;
        const float QSCALE = 0.18033688011112042f;   // 0.125 * log2(e)
        float f0 = expf(-(float)lr * LN1E4_D32);          // jj = lr
        float f1 = expf(-(float)(16 + lr) * LN1E4_D32);   // jj = 16+lr
        #pragma unroll
        for (int s = 0; s < 2; ++s) {
            #pragma unroll
            for (int r = 0; r < 4; ++r) {
                int n = n0 + 64 * s + 16 * w + 4 * lq + r;
                float c0v, s0v, c1v, s1v;
                sincosf((float)n * f0, &s0v, &c0v);
                sincosf((float)n * f1, &s1v, &c1v);
                float q0 = acc[s][0][r], q1 = acc[s][1][r];
                float q2 = acc[s][2][r], q3 = acc[s][3][r];
                // j=lr (nt0): rot=-q2 ; j=16+lr (nt1): rot=-q3
                // j=32+lr (nt2): rot=+q0 ; j=48+lr (nt3): rot=+q1
                Ps[64 * s + 16 * w + 4 * lq + r][lr]      = f2b(QSCALE * (q0 * c0v - q2 * s0v));
                Ps[64 * s + 16 * w + 4 * lq + r][16 + lr] = f2b(QSCALE * (q1 * c1v - q3 * s1v));
                Ps[64 * s + 16 * w + 4 * lq + r][32 + lr] = f2b(QSCALE * (q2 * c0v + q0 * s0v));
                Ps[64 * s + 16 * w + 4 * lq + r][48 + lr] = f2b(QSCALE * (q3 * c1v + q1 * s1v));
            }
        }
    }
    __syncthreads();
    v8s aq[2][2];                                  // Q A-fragments, wave-private
    #pragma unroll
    for (int s = 0; s < 2; ++s)
        #pragma unroll
        for (int ks = 0; ks < 2; ++ks)
            aq[s][ks] = *(const v8s*)&Ps[64 * s + 16 * w + lr][32 * ks + 8 * lq];

    // ---- Phase 2: flash loop over 64-key chunks ----
    float mrun[2][4], lrun[2][4];
    #pragma unroll
    for (int s = 0; s < 2; ++s)
        for (int r = 0; r < 4; ++r) { mrun[s][r] = -1e30f; lrun[s][r] = 0.f; }
    v4f o[2][4];
    #pragma unroll
    for (int s = 0; s < 2; ++s)
        for (int nt = 0; nt < 4; ++nt)
            for (int r = 0; r < 4; ++r) o[s][nt][r] = 0.f;

    const int r2 = tid >> 2, cc = (tid & 3) * 16;
    const short* __restrict__ Kb = K + (size_t)bh * SEQ * HD;
    const short* __restrict__ Vb = Vt + (size_t)bh * HD * SEQ;

    for (int c0 = 0; c0 < SEQ; c0 += 64) {
        v8s k1 = *(const v8s*)&Kb[(size_t)(c0 + r2) * HD + cc];
        v8s k2 = *(const v8s*)&Kb[(size_t)(c0 + r2) * HD + cc + 8];
        v8s v1 = *(const v8s*)&Vb[(size_t)r2 * SEQ + c0 + cc];
        v8s v2 = *(const v8s*)&Vb[(size_t)r2 * SEQ + c0 + cc + 8];
        __syncthreads();                      // prev chunk LDS reads done
        *(v8s*)&u.p2.Ks[r2][cc] = k1;
        *(v8s*)&u.p2.Ks[r2][cc + 8] = k2;
        *(v8s*)&u.p2.Vs[r2][cc] = v1;
        *(v8s*)&u.p2.Vs[r2][cc + 8] = v2;
        if (tid < 64) mbias[tid] = mask[b * SEQ + c0 + tid] ? 0.f : -1e30f;
        __syncthreads();

        #pragma unroll
        for (int s = 0; s < 2; ++s) {
            // S = Q @ K^T (log2-domain scale pre-folded into Q)
            v4f sv[4];
            #pragma unroll
            for (int nt = 0; nt < 4; ++nt)
                for (int r = 0; r < 4; ++r) sv[nt][r] = 0.f;
            #pragma unroll
            for (int ks = 0; ks < 2; ++ks) {
                #pragma unroll
                for (int nt = 0; nt < 4; ++nt) {
                    v8s bb = *(const v8s*)&u.p2.Ks[16 * nt + lr][32 * ks + 8 * lq];
                    sv[nt] = MFMA16(aq[s][ks], bb, sv[nt]);
                }
            }
            // additive mask bias
            #pragma unroll
            for (int nt = 0; nt < 4; ++nt) {
                float bias = mbias[16 * nt + lr];
                #pragma unroll
                for (int r = 0; r < 4; ++r) sv[nt][r] += bias;
            }
            // online softmax (exp2 domain), butterfly over 16-lane col group
            float alpha[4];
            #pragma unroll
            for (int r = 0; r < 4; ++r) {
                float mc = fmaxf(fmaxf(sv[0][r], sv[1][r]), fmaxf(sv[2][r], sv[3][r]));
                mc = fmaxf(mc, __shfl_xor(mc, 1));
                mc = fmaxf(mc, __shfl_xor(mc, 2));
                mc = fmaxf(mc, __shfl_xor(mc, 4));
                mc = fmaxf(mc, __shfl_xor(mc, 8));
                float mnew = fmaxf(mrun[s][r], mc);
                alpha[r] = exp2f(mrun[s][r] - mnew);
                mrun[s][r] = mnew;
            }
            float rs[4] = {0.f, 0.f, 0.f, 0.f};
            #pragma unroll
            for (int nt = 0; nt < 4; ++nt) {
                #pragma unroll
                for (int r = 0; r < 4; ++r) {
                    float p = exp2f(sv[nt][r] - mrun[s][r]);
                    rs[r] += p;
                    Ps[64 * s + 16 * w + 4 * lq + r][16 * nt + lr] = f2b(p);
                }
            }
            #pragma unroll
            for (int r = 0; r < 4; ++r) {
                rs[r] += __shfl_xor(rs[r], 1);
                rs[r] += __shfl_xor(rs[r], 2);
                rs[r] += __shfl_xor(rs[r], 4);
                rs[r] += __shfl_xor(rs[r], 8);
                lrun[s][r] = lrun[s][r] * alpha[r] + rs[r];
            }
            #pragma unroll
            for (int nt = 0; nt < 4; ++nt)
                #pragma unroll
                for (int r = 0; r < 4; ++r) o[s][nt][r] *= alpha[r];

            // O += P @ V  (Ps row-strip is wave-private: no barrier needed)
            #pragma unroll
            for (int ks = 0; ks < 2; ++ks) {
                v8s a = *(const v8s*)&Ps[64 * s + 16 * w + lr][32 * ks + 8 * lq];
                #pragma unroll
                for (int nt = 0; nt < 4; ++nt) {
                    v8s bb = *(const v8s*)&u.p2.Vs[16 * nt + lr][32 * ks + 8 * lq];
                    o[s][nt] = MFMA16(a, bb, o[s][nt]);
                }
            }
        }
    }

    // ---- finalize (all-masked rows -> 0 via mrun guard) ----
    #pragma unroll
    for (int s = 0; s < 2; ++s) {
        #pragma unroll
        for (int r = 0; r < 4; ++r) {
            float inv = (mrun[s][r] > -1e29f && lrun[s][r] > 0.f)
                        ? 1.f / lrun[s][r] : 0.f;
            int qrow = 64 * s + 16 * w + 4 * lq + r;
            #pragma unroll
            for (int nt = 0; nt < 4; ++nt)
                O[(size_t)(m0 + qrow) * DM + h * HD + 16 * nt + lr] =
                    f2b(o[s][nt][r] * inv);
        }
    }
}

// ---------------------------------------------------------------------------
// Kernel 3: out = O @ Wo^T via MFMA (exact R5 structure), fp32 store.
// grid = (MTOT/64, DM/64).
// ---------------------------------------------------------------------------
__global__ __launch_bounds__(256) void oproj_mfma(
    const short* __restrict__ O, const short* __restrict__ Wob,
    float* __restrict__ out)
{
    const int m0 = blockIdx.x * 64, e0 = blockIdx.y * 64;
    const int tid = threadIdx.x;
    const int w = tid >> 6, lane = tid & 63, lq = lane >> 4, lr = lane & 15;
    const int sr = tid >> 2, sc = (tid & 3) * 8;

    __shared__ short As[64][32];
    __shared__ short Bs[64][32];

    v4f acc[4];
    #pragma unroll
    for (int nt = 0; nt < 4; ++nt)
        for (int r = 0; r < 4; ++r) acc[nt][r] = 0.f;

    for (int k0 = 0; k0 < DM; k0 += 32) {
        v8s av = *(const v8s*)&O[(size_t)(m0 + sr) * DM + k0 + sc];
        v8s bv = *(const v8s*)&Wob[(size_t)(e0 + sr) * DM + k0 + sc];
        __syncthreads();
        *(v8s*)&As[sr][sc] = av;
        *(v8s*)&Bs[sr][sc] = bv;
        __syncthreads();
        v8s a = *(const v8s*)&As[16 * w + lr][lq * 8];
        #pragma unroll
        for (int nt = 0; nt < 4; ++nt) {
            v8s bb = *(const v8s*)&Bs[16 * nt + lr][lq * 8];
            acc[nt] = MFMA16(a, bb, acc[nt]);
        }
    }

    #pragma unroll
    for (int r = 0; r < 4; ++r) {
        int m = m0 + 16 * w + lq * 4 + r;
        #pragma unroll
        for (int nt = 0; nt < 4; ++nt)
            out[(size_t)m * DM + e0 + 16 * nt + lr] = acc[nt][r];
    }
}

// ---------------------------------------------------------------------------
extern "C" void kernel_launch(void* const* d_in, const int* in_sizes, int n_in,
                              void* d_out, int out_size, void* d_ws, size_t ws_size,
                              hipStream_t stream)
{
    const float* x    = (const float*)d_in[0];
    const int*   mask = (const int*)d_in[1];
    const float* Wq   = (const float*)d_in[2];
    const float* Wk   = (const float*)d_in[3];
    const float* Wv   = (const float*)d_in[4];
    const float* Wo   = (const float*)d_in[5];
    float* out = (float*)d_out;

    // ws (24 MiB of shorts): xb | Wqb | Wkb | Wvb | Wob | O
    short* xb  = (short*)d_ws;                    // 4 Mi
    short* Wqb = xb  + (size_t)MTOT * DM;         // 1 Mi each
    short* Wkb = Wqb + (size_t)DM * DM;
    short* Wvb = Wkb + (size_t)DM * DM;
    short* Wob = Wvb + (size_t)DM * DM;
    short* O   = Wob + (size_t)DM * DM;           // 4 Mi
    // d_out (16 MiB) doubles as K/Vt scratch until the final projection
    short* K  = (short*)d_out;                    // 4 Mi
    short* Vt = K + (size_t)MTOT * DM;            // 4 Mi

    const int NX8 = MTOT * DM / 8, NW8 = DM * DM / 8;
    cvt_kernel<<<(NX8 + 255) / 256, 256, 0, stream>>>(x, xb, NX8);
    cvt_kernel<<<(NW8 + 255) / 256, 256, 0, stream>>>(Wq, Wqb, NW8);
    cvt_kernel<<<(NW8 + 255) / 256, 256, 0, stream>>>(Wk, Wkb, NW8);
    cvt_kernel<<<(NW8 + 255) / 256, 256, 0, stream>>>(Wv, Wvb, NW8);
    cvt_kernel<<<(NW8 + 255) / 256, 256, 0, stream>>>(Wo, Wob, NW8);

    dim3 g1(MTOT / 64, NH, 2);
    kv_rope_mfma<<<g1, 256, 0, stream>>>(xb, Wkb, Wvb, K, Vt);

    dim3 g2(MTOT / 128, NH);
    attn_mfma<<<g2, 256, 0, stream>>>(xb, Wqb, K, Vt, mask, O);

    dim3 g3(MTOT / 64, DM / 64);
    oproj_mfma<<<g3, 256, 0, stream>>>(O, Wob, out);
}

// Round 8
// 261.670 us; speedup vs baseline: 1.8083x; 1.2238x over previous
//
#include <hip/hip_runtime.h>
#include <math.h>

#define BATCH 2
#define SEQ   2048
#define DM    1024
#define NH    16
#define HD    64
#define MTOT  (BATCH*SEQ)            // 4096

typedef short v8s __attribute__((ext_vector_type(8)));   // 8 bf16 = 4 VGPR
typedef short v4s __attribute__((ext_vector_type(4)));
typedef float v4f __attribute__((ext_vector_type(4)));

#define MFMA16(a, b, c) __builtin_amdgcn_mfma_f32_16x16x32_bf16((a), (b), (c), 0, 0, 0)

__device__ __forceinline__ short f2b(float f) {          // fp32 -> bf16 bits, RNE
    union { float f; unsigned u; } v; v.f = f;
    unsigned r = (v.u + 0x7FFFu + ((v.u >> 16) & 1u)) >> 16;
    return (short)r;
}

// ---------------------------------------------------------------------------
// Kernel 0: fp32 -> bf16-bits elementwise convert (8 elems / thread).
// ---------------------------------------------------------------------------
__global__ __launch_bounds__(256) void cvt_kernel(
    const float* __restrict__ src, short* __restrict__ dst, int n8)
{
    int i = blockIdx.x * 256 + threadIdx.x;
    if (i >= n8) return;
    const float4* s4 = (const float4*)src;
    float4 a = s4[2 * i], b = s4[2 * i + 1];
    v8s p;
    p[0] = f2b(a.x); p[1] = f2b(a.y); p[2] = f2b(a.z); p[3] = f2b(a.w);
    p[4] = f2b(b.x); p[5] = f2b(b.y); p[6] = f2b(b.z); p[7] = f2b(b.w);
    *(v8s*)&dst[8 * i] = p;
}

// ---------------------------------------------------------------------------
// Kernel 1: K/V projections, 128x128 MFMA tile (m93 pattern).
//   z=0: K = RoPE(x @ Wk^T) -> [bh][key][d]   (RoPE in-register)
//   z=1: V = x @ Wv^T -> Vt[bh][d][key]       (transposed via LDS)
// 256 thr / 4 waves in 2x2 quadrants; wave (wm,wn) owns rows 64wm+, cols 64wn+.
// Each wave's 64 cols == one head. grid = (MTOT/128, DM/128, 2).
// ---------------------------------------------------------------------------
__global__ __launch_bounds__(256) void kv_rope_mfma(
    const short* __restrict__ xb, const short* __restrict__ Wkb,
    const short* __restrict__ Wvb, short* __restrict__ K, short* __restrict__ Vt)
{
    const int zz = blockIdx.z;
    const short* __restrict__ Wb = zz ? Wvb : Wkb;
    const int m0 = blockIdx.x * 128, e00 = blockIdx.y * 128;
    const int tid = threadIdx.x;
    const int w = tid >> 6, lane = tid & 63, lq = lane >> 4, lr = lane & 15;
    const int wm = w >> 1, wn = w & 1;

    __shared__ union {
        struct { short As[128][32]; short Bs[128][32]; } p1;  // 16 KB
        short Css[128][136];                                   // 34 KB
    } u;

    v4f acc[4][4];
    #pragma unroll
    for (int i = 0; i < 4; ++i)
        for (int j = 0; j < 4; ++j)
            for (int r = 0; r < 4; ++r) acc[i][j][r] = 0.f;

    const int arow = tid >> 1, aseg = (tid & 1) * 16;
    for (int k0 = 0; k0 < DM; k0 += 32) {
        v8s a0 = *(const v8s*)&xb[(size_t)(m0 + arow) * DM + k0 + aseg];
        v8s a1 = *(const v8s*)&xb[(size_t)(m0 + arow) * DM + k0 + aseg + 8];
        v8s b0 = *(const v8s*)&Wb[(size_t)(e00 + arow) * DM + k0 + aseg];
        v8s b1 = *(const v8s*)&Wb[(size_t)(e00 + arow) * DM + k0 + aseg + 8];
        __syncthreads();
        *(v8s*)&u.p1.As[arow][aseg] = a0;
        *(v8s*)&u.p1.As[arow][aseg + 8] = a1;
        *(v8s*)&u.p1.Bs[arow][aseg] = b0;
        *(v8s*)&u.p1.Bs[arow][aseg + 8] = b1;
        __syncthreads();
        v8s af[4], bf[4];
        #pragma unroll
        for (int i = 0; i < 4; ++i)
            af[i] = *(const v8s*)&u.p1.As[64 * wm + 16 * i + lr][8 * lq];
        #pragma unroll
        for (int j = 0; j < 4; ++j)
            bf[j] = *(const v8s*)&u.p1.Bs[64 * wn + 16 * j + lr][8 * lq];
        #pragma unroll
        for (int i = 0; i < 4; ++i)
            #pragma unroll
            for (int j = 0; j < 4; ++j)
                acc[i][j] = MFMA16(af[i], bf[j], acc[i][j]);
    }
    __syncthreads();   // k-loop LDS reads done before Css overwrite

    const int b = m0 >> 11, n00 = m0 & (SEQ - 1);
    const float LN1E4_D32 = 0.28782313662425572f;   // ln(10000)/32

    if (zz == 0) {
        // RoPE in-register (cols of this wave = one head; pairs j <-> j^2)
        float f0 = expf(-(float)lr * LN1E4_D32);
        float f1 = expf(-(float)(16 + lr) * LN1E4_D32);
        #pragma unroll
        for (int i = 0; i < 4; ++i) {
            #pragma unroll
            for (int r = 0; r < 4; ++r) {
                int row = 64 * wm + 16 * i + 4 * lq + r;
                int n = n00 + row;
                float c0v, s0v, c1v, s1v;
                sincosf((float)n * f0, &s0v, &c0v);
                sincosf((float)n * f1, &s1v, &c1v);
                float q0 = acc[i][0][r], q1 = acc[i][1][r];
                float q2 = acc[i][2][r], q3 = acc[i][3][r];
                u.Css[row][64 * wn + lr]      = f2b(q0 * c0v - q2 * s0v);
                u.Css[row][64 * wn + 16 + lr] = f2b(q1 * c1v - q3 * s1v);
                u.Css[row][64 * wn + 32 + lr] = f2b(q2 * c0v + q0 * s0v);
                u.Css[row][64 * wn + 48 + lr] = f2b(q3 * c1v + q1 * s1v);
            }
        }
        __syncthreads();
        int row = tid >> 1, hh = tid & 1;
        int h = (e00 >> 6) + hh;
        int n = n00 + row;
        size_t base = (((size_t)(b * NH + h)) * SEQ + n) * HD;
        #pragma unroll
        for (int p = 0; p < 8; ++p)
            *(v8s*)&K[base + 8 * p] = *(const v8s*)&u.Css[row][64 * hh + 8 * p];
    } else {
        // V transposed: Css_T[col][row], packed b64 along row (r contiguous)
        #pragma unroll
        for (int i = 0; i < 4; ++i) {
            #pragma unroll
            for (int j = 0; j < 4; ++j) {
                v4s t;
                #pragma unroll
                for (int r = 0; r < 4; ++r) t[r] = f2b(acc[i][j][r]);
                *(v4s*)&u.Css[64 * wn + 16 * j + lr][64 * wm + 16 * i + 4 * lq] = t;
            }
        }
        __syncthreads();
        int c = tid >> 1, half = (tid & 1) * 64;
        int h = (e00 + c) >> 6, d = (e00 + c) & 63;
        size_t base = (((size_t)(b * NH + h)) * HD + d) * SEQ + n00 + half;
        #pragma unroll
        for (int p = 0; p < 8; ++p)
            *(v8s*)&Vt[base + 8 * p] = *(const v8s*)&u.Css[c][half + 8 * p];
    }
}

// ---------------------------------------------------------------------------
// Kernel 2: fused Q-proj + RoPE + flash attention, 128-row Q-tile.
// FIXED-MAX softmax (M=24, folded into mask bias): no running max, no alpha,
// no per-chunk shuffle reduce — l accumulates in-register, one butterfly at end.
// grid = (MTOT/128, NH), 256 threads / 4 waves.
// ---------------------------------------------------------------------------
__global__ __launch_bounds__(256) void attn_mfma(
    const short* __restrict__ xb, const short* __restrict__ Wqb,
    const short* __restrict__ K, const short* __restrict__ Vt,
    const int* __restrict__ mask, short* __restrict__ O)
{
    const int m0 = blockIdx.x * 128, h = blockIdx.y, e0 = h * 64;
    const int b = m0 >> 11, n0 = m0 & (SEQ - 1), bh = b * NH + h;
    const int tid = threadIdx.x;
    const int w = tid >> 6, lane = tid & 63, lq = lane >> 4, lr = lane & 15;
    const int sr = tid >> 2, sc = (tid & 3) * 8;

    __shared__ union {
        struct { short As[128][32]; short Bs[64][32]; } p1;   // 12 KB
        struct { short Ks[64][72]; short Vs[64][72]; } p2;    // 18.4 KB
    } u;
    __shared__ short Ps[128][72];                             // 18.4 KB
    __shared__ float mbias[64];

    // ---- Phase 1: Q[128][64] = x_tile @ Wq_h^T ----
    v4f acc[2][4];
    #pragma unroll
    for (int s = 0; s < 2; ++s)
        for (int nt = 0; nt < 4; ++nt)
            for (int r = 0; r < 4; ++r) acc[s][nt][r] = 0.f;

    for (int k0 = 0; k0 < DM; k0 += 32) {
        v8s a0 = *(const v8s*)&xb[(size_t)(m0 + sr) * DM + k0 + sc];
        v8s a1 = *(const v8s*)&xb[(size_t)(m0 + 64 + sr) * DM + k0 + sc];
        v8s bv = *(const v8s*)&Wqb[(size_t)(e0 + sr) * DM + k0 + sc];
        __syncthreads();
        *(v8s*)&u.p1.As[sr][sc] = a0;
        *(v8s*)&u.p1.As[64 + sr][sc] = a1;
        *(v8s*)&u.p1.Bs[sr][sc] = bv;
        __syncthreads();
        v8s aw0 = *(const v8s*)&u.p1.As[16 * w + lr][lq * 8];
        v8s aw1 = *(const v8s*)&u.p1.As[64 + 16 * w + lr][lq * 8];
        #pragma unroll
        for (int nt = 0; nt < 4; ++nt) {
            v8s bb = *(const v8s*)&u.p1.Bs[16 * nt + lr][lq * 8];
            acc[0][nt] = MFMA16(aw0, bb, acc[0][nt]);
            acc[1][nt] = MFMA16(aw1, bb, acc[1][nt]);
        }
    }

    // ---- RoPE in registers (pair nt <-> nt^2 is j <-> j^32), fold scale ----
    {
        const float LN1E4_D32 = 0.28782313662425572f;
        const float QSCALE = 0.18033688011112042f;   // 0.125 * log2(e)
        float f0 = expf(-(float)lr * LN1E4_D32);          // jj = lr
        float f1 = expf(-(float)(16 + lr) * LN1E4_D32);   // jj = 16+lr
        #pragma unroll
        for (int s = 0; s < 2; ++s) {
            #pragma unroll
            for (int r = 0; r < 4; ++r) {
                int n = n0 + 64 * s + 16 * w + 4 * lq + r;
                float c0v, s0v, c1v, s1v;
                sincosf((float)n * f0, &s0v, &c0v);
                sincosf((float)n * f1, &s1v, &c1v);
                float q0 = acc[s][0][r], q1 = acc[s][1][r];
                float q2 = acc[s][2][r], q3 = acc[s][3][r];
                Ps[64 * s + 16 * w + 4 * lq + r][lr]      = f2b(QSCALE * (q0 * c0v - q2 * s0v));
                Ps[64 * s + 16 * w + 4 * lq + r][16 + lr] = f2b(QSCALE * (q1 * c1v - q3 * s1v));
                Ps[64 * s + 16 * w + 4 * lq + r][32 + lr] = f2b(QSCALE * (q2 * c0v + q0 * s0v));
                Ps[64 * s + 16 * w + 4 * lq + r][48 + lr] = f2b(QSCALE * (q3 * c1v + q1 * s1v));
            }
        }
    }
    __syncthreads();
    v8s aq[2][2];                                  // Q A-fragments, wave-private
    #pragma unroll
    for (int s = 0; s < 2; ++s)
        #pragma unroll
        for (int ks = 0; ks < 2; ++ks)
            aq[s][ks] = *(const v8s*)&Ps[64 * s + 16 * w + lr][32 * ks + 8 * lq];

    // ---- Phase 2: flash loop, fixed-max softmax (M = 24 in log2 domain) ----
    float lacc[2][4];
    #pragma unroll
    for (int s = 0; s < 2; ++s)
        for (int r = 0; r < 4; ++r) lacc[s][r] = 0.f;
    v4f o[2][4];
    #pragma unroll
    for (int s = 0; s < 2; ++s)
        for (int nt = 0; nt < 4; ++nt)
            for (int r = 0; r < 4; ++r) o[s][nt][r] = 0.f;

    const int r2 = tid >> 2, cc = (tid & 3) * 16;
    const short* __restrict__ Kb = K + (size_t)bh * SEQ * HD;
    const short* __restrict__ Vb = Vt + (size_t)bh * HD * SEQ;

    for (int c0 = 0; c0 < SEQ; c0 += 64) {
        v8s k1 = *(const v8s*)&Kb[(size_t)(c0 + r2) * HD + cc];
        v8s k2 = *(const v8s*)&Kb[(size_t)(c0 + r2) * HD + cc + 8];
        v8s v1 = *(const v8s*)&Vb[(size_t)r2 * SEQ + c0 + cc];
        v8s v2 = *(const v8s*)&Vb[(size_t)r2 * SEQ + c0 + cc + 8];
        __syncthreads();                      // prev chunk LDS reads done
        *(v8s*)&u.p2.Ks[r2][cc] = k1;
        *(v8s*)&u.p2.Ks[r2][cc + 8] = k2;
        *(v8s*)&u.p2.Vs[r2][cc] = v1;
        *(v8s*)&u.p2.Vs[r2][cc + 8] = v2;
        if (tid < 64) mbias[tid] = mask[b * SEQ + c0 + tid] ? -24.0f : -1e30f;
        __syncthreads();

        #pragma unroll
        for (int s = 0; s < 2; ++s) {
            // S = Q @ K^T (log2-domain scale pre-folded into Q)
            v4f sv[4];
            #pragma unroll
            for (int nt = 0; nt < 4; ++nt)
                for (int r = 0; r < 4; ++r) sv[nt][r] = 0.f;
            #pragma unroll
            for (int ks = 0; ks < 2; ++ks) {
                #pragma unroll
                for (int nt = 0; nt < 4; ++nt) {
                    v8s bb = *(const v8s*)&u.p2.Ks[16 * nt + lr][32 * ks + 8 * lq];
                    sv[nt] = MFMA16(aq[s][ks], bb, sv[nt]);
                }
            }
            // p = exp2(s + bias - 24); masked bias -1e30 underflows to 0
            #pragma unroll
            for (int nt = 0; nt < 4; ++nt) {
                float bias = mbias[16 * nt + lr];
                #pragma unroll
                for (int r = 0; r < 4; ++r) {
                    float p = exp2f(sv[nt][r] + bias);
                    lacc[s][r] += p;
                    Ps[64 * s + 16 * w + 4 * lq + r][16 * nt + lr] = f2b(p);
                }
            }
            // O += P @ V  (Ps row-strip is wave-private: no barrier needed)
            #pragma unroll
            for (int ks = 0; ks < 2; ++ks) {
                v8s a = *(const v8s*)&Ps[64 * s + 16 * w + lr][32 * ks + 8 * lq];
                #pragma unroll
                for (int nt = 0; nt < 4; ++nt) {
                    v8s bb = *(const v8s*)&u.p2.Vs[16 * nt + lr][32 * ks + 8 * lq];
                    o[s][nt] = MFMA16(a, bb, o[s][nt]);
                }
            }
        }
    }

    // ---- finalize: one butterfly per row; all-masked rows -> l=0 -> 0 ----
    #pragma unroll
    for (int s = 0; s < 2; ++s) {
        #pragma unroll
        for (int r = 0; r < 4; ++r) {
            float l = lacc[s][r];
            l += __shfl_xor(l, 1);
            l += __shfl_xor(l, 2);
            l += __shfl_xor(l, 4);
            l += __shfl_xor(l, 8);
            float inv = (l > 0.f) ? 1.f / l : 0.f;
            int qrow = 64 * s + 16 * w + 4 * lq + r;
            #pragma unroll
            for (int nt = 0; nt < 4; ++nt)
                O[(size_t)(m0 + qrow) * DM + h * HD + 16 * nt + lr] =
                    f2b(o[s][nt][r] * inv);
        }
    }
}

// ---------------------------------------------------------------------------
// Kernel 3: out = O @ Wo^T, 128x128 MFMA tile, fp32 direct stores.
// grid = (MTOT/128, DM/128).
// ---------------------------------------------------------------------------
__global__ __launch_bounds__(256) void oproj_mfma(
    const short* __restrict__ O, const short* __restrict__ Wob,
    float* __restrict__ out)
{
    const int m0 = blockIdx.x * 128, e00 = blockIdx.y * 128;
    const int tid = threadIdx.x;
    const int w = tid >> 6, lane = tid & 63, lq = lane >> 4, lr = lane & 15;
    const int wm = w >> 1, wn = w & 1;

    __shared__ short As[128][32];
    __shared__ short Bs[128][32];

    v4f acc[4][4];
    #pragma unroll
    for (int i = 0; i < 4; ++i)
        for (int j = 0; j < 4; ++j)
            for (int r = 0; r < 4; ++r) acc[i][j][r] = 0.f;

    const int arow = tid >> 1, aseg = (tid & 1) * 16;
    for (int k0 = 0; k0 < DM; k0 += 32) {
        v8s a0 = *(const v8s*)&O[(size_t)(m0 + arow) * DM + k0 + aseg];
        v8s a1 = *(const v8s*)&O[(size_t)(m0 + arow) * DM + k0 + aseg + 8];
        v8s b0 = *(const v8s*)&Wob[(size_t)(e00 + arow) * DM + k0 + aseg];
        v8s b1 = *(const v8s*)&Wob[(size_t)(e00 + arow) * DM + k0 + aseg + 8];
        __syncthreads();
        *(v8s*)&As[arow][aseg] = a0;
        *(v8s*)&As[arow][aseg + 8] = a1;
        *(v8s*)&Bs[arow][aseg] = b0;
        *(v8s*)&Bs[arow][aseg + 8] = b1;
        __syncthreads();
        v8s af[4], bf[4];
        #pragma unroll
        for (int i = 0; i < 4; ++i)
            af[i] = *(const v8s*)&As[64 * wm + 16 * i + lr][8 * lq];
        #pragma unroll
        for (int j = 0; j < 4; ++j)
            bf[j] = *(const v8s*)&Bs[64 * wn + 16 * j + lr][8 * lq];
        #pragma unroll
        for (int i = 0; i < 4; ++i)
            #pragma unroll
            for (int j = 0; j < 4; ++j)
                acc[i][j] = MFMA16(af[i], bf[j], acc[i][j]);
    }

    #pragma unroll
    for (int i = 0; i < 4; ++i)
        #pragma unroll
        for (int r = 0; r < 4; ++r) {
            int m = m0 + 64 * wm + 16 * i + 4 * lq + r;
            #pragma unroll
            for (int j = 0; j < 4; ++j)
                out[(size_t)m * DM + e00 + 64 * wn + 16 * j + lr] = acc[i][j][r];
        }
}

// ---------------------------------------------------------------------------
extern "C" void kernel_launch(void* const* d_in, const int* in_sizes, int n_in,
                              void* d_out, int out_size, void* d_ws, size_t ws_size,
                              hipStream_t stream)
{
    const float* x    = (const float*)d_in[0];
    const int*   mask = (const int*)d_in[1];
    const float* Wq   = (const float*)d_in[2];
    const float* Wk   = (const float*)d_in[3];
    const float* Wv   = (const float*)d_in[4];
    const float* Wo   = (const float*)d_in[5];
    float* out = (float*)d_out;

    // ws (24 MiB of shorts): xb | Wqb | Wkb | Wvb | Wob | O
    short* xb  = (short*)d_ws;                    // 4 Mi
    short* Wqb = xb  + (size_t)MTOT * DM;         // 1 Mi each
    short* Wkb = Wqb + (size_t)DM * DM;
    short* Wvb = Wkb + (size_t)DM * DM;
    short* Wob = Wvb + (size_t)DM * DM;
    short* O   = Wob + (size_t)DM * DM;           // 4 Mi
    // d_out (16 MiB) doubles as K/Vt scratch until the final projection
    short* K  = (short*)d_out;                    // 4 Mi
    short* Vt = K + (size_t)MTOT * DM;            // 4 Mi

    const int NX8 = MTOT * DM / 8, NW8 = DM * DM / 8;
    cvt_kernel<<<(NX8 + 255) / 256, 256, 0, stream>>>(x, xb, NX8);
    cvt_kernel<<<(NW8 + 255) / 256, 256, 0, stream>>>(Wq, Wqb, NW8);
    cvt_kernel<<<(NW8 + 255) / 256, 256, 0, stream>>>(Wk, Wkb, NW8);
    cvt_kernel<<<(NW8 + 255) / 256, 256, 0, stream>>>(Wv, Wvb, NW8);
    cvt_kernel<<<(NW8 + 255) / 256, 256, 0, stream>>>(Wo, Wob, NW8);

    dim3 g1(MTOT / 128, DM / 128, 2);
    kv_rope_mfma<<<g1, 256, 0, stream>>>(xb, Wkb, Wvb, K, Vt);

    dim3 g2(MTOT / 128, NH);
    attn_mfma<<<g2, 256, 0, stream>>>(xb, Wqb, K, Vt, mask, O);

    dim3 g3(MTOT / 128, DM / 128);
    oproj_mfma<<<g3, 256, 0, stream>>>(O, Wob, out);
}

// Round 9
// 221.798 us; speedup vs baseline: 2.1334x; 1.1798x over previous
//
#include <hip/hip_runtime.h>
#include <math.h>

#define BATCH 2
#define SEQ   2048
#define DM    1024
#define NH    16
#define HD    64
#define MTOT  (BATCH*SEQ)            // 4096

typedef short v8s __attribute__((ext_vector_type(8)));   // 8 bf16 = 4 VGPR
typedef short v4s __attribute__((ext_vector_type(4)));
typedef float v4f __attribute__((ext_vector_type(4)));

#define MFMA16(a, b, c) __builtin_amdgcn_mfma_f32_16x16x32_bf16((a), (b), (c), 0, 0, 0)

__device__ __forceinline__ short f2b(float f) {   // fp32->bf16, round-half-up
    union { float f; unsigned u; } v; v.f = f;    // (== RNE except exact ties)
    return (short)((v.u + 0x8000u) >> 16);
}

// ---------------------------------------------------------------------------
// Kernel 0: fused fp32 -> bf16 convert for x | Wq | Wk | Wv | Wo into one
// contiguous dst (the ws base). 8 elems/thread, 1Mi threads.
// ---------------------------------------------------------------------------
__global__ __launch_bounds__(256) void cvt_all_kernel(
    const float* __restrict__ x,  const float* __restrict__ wq,
    const float* __restrict__ wk, const float* __restrict__ wv,
    const float* __restrict__ wo, short* __restrict__ dst)
{
    int i = blockIdx.x * 256 + threadIdx.x;            // < 1 Mi
    const float* src; int off;
    if (i < (1 << 19)) { src = x; off = i; }
    else {
        int j = i - (1 << 19);
        int wsel = j >> 17;
        off = j & ((1 << 17) - 1);
        src = (wsel == 0) ? wq : (wsel == 1) ? wk : (wsel == 2) ? wv : wo;
    }
    const float4* s4 = (const float4*)src;
    float4 a = s4[2 * off], b = s4[2 * off + 1];
    v8s p;
    p[0] = f2b(a.x); p[1] = f2b(a.y); p[2] = f2b(a.z); p[3] = f2b(a.w);
    p[4] = f2b(b.x); p[5] = f2b(b.y); p[6] = f2b(b.z); p[7] = f2b(b.w);
    *(v8s*)&dst[8 * i] = p;
}

// ---------------------------------------------------------------------------
// Kernel 1: K/V projections, 128x128 MFMA tile.
//   z=0: K = RoPE(x @ Wk^T) -> [bh][key][d]   (RoPE in-register)
//   z=1: V = x @ Wv^T -> Vt[bh][d][key]       (transposed via LDS)
// grid = (MTOT/128, DM/128, 2). 2 blocks/CU.
// ---------------------------------------------------------------------------
__global__ __launch_bounds__(256, 2) void kv_rope_mfma(
    const short* __restrict__ xb, const short* __restrict__ Wkb,
    const short* __restrict__ Wvb, short* __restrict__ K, short* __restrict__ Vt)
{
    const int zz = blockIdx.z;
    const short* __restrict__ Wb = zz ? Wvb : Wkb;
    const int m0 = blockIdx.x * 128, e00 = blockIdx.y * 128;
    const int tid = threadIdx.x;
    const int w = tid >> 6, lane = tid & 63, lq = lane >> 4, lr = lane & 15;
    const int wm = w >> 1, wn = w & 1;

    __shared__ union {
        struct { short As[128][32]; short Bs[128][32]; } p1;  // 16 KB
        short Css[128][136];                                   // 34 KB
    } u;

    v4f acc[4][4];
    #pragma unroll
    for (int i = 0; i < 4; ++i)
        for (int j = 0; j < 4; ++j)
            for (int r = 0; r < 4; ++r) acc[i][j][r] = 0.f;

    const int arow = tid >> 1, aseg = (tid & 1) * 16;
    for (int k0 = 0; k0 < DM; k0 += 32) {
        v8s a0 = *(const v8s*)&xb[(size_t)(m0 + arow) * DM + k0 + aseg];
        v8s a1 = *(const v8s*)&xb[(size_t)(m0 + arow) * DM + k0 + aseg + 8];
        v8s b0 = *(const v8s*)&Wb[(size_t)(e00 + arow) * DM + k0 + aseg];
        v8s b1 = *(const v8s*)&Wb[(size_t)(e00 + arow) * DM + k0 + aseg + 8];
        __syncthreads();
        *(v8s*)&u.p1.As[arow][aseg] = a0;
        *(v8s*)&u.p1.As[arow][aseg + 8] = a1;
        *(v8s*)&u.p1.Bs[arow][aseg] = b0;
        *(v8s*)&u.p1.Bs[arow][aseg + 8] = b1;
        __syncthreads();
        v8s af[4], bf[4];
        #pragma unroll
        for (int i = 0; i < 4; ++i)
            af[i] = *(const v8s*)&u.p1.As[64 * wm + 16 * i + lr][8 * lq];
        #pragma unroll
        for (int j = 0; j < 4; ++j)
            bf[j] = *(const v8s*)&u.p1.Bs[64 * wn + 16 * j + lr][8 * lq];
        #pragma unroll
        for (int i = 0; i < 4; ++i)
            #pragma unroll
            for (int j = 0; j < 4; ++j)
                acc[i][j] = MFMA16(af[i], bf[j], acc[i][j]);
    }
    __syncthreads();   // k-loop LDS reads done before Css overwrite

    const int b = m0 >> 11, n00 = m0 & (SEQ - 1);
    const float LN1E4_D32 = 0.28782313662425572f;   // ln(10000)/32

    if (zz == 0) {
        // RoPE in-register (cols of this wave = one head; pairs nt <-> nt^2)
        float f0 = expf(-(float)lr * LN1E4_D32);
        float f1 = expf(-(float)(16 + lr) * LN1E4_D32);
        #pragma unroll
        for (int i = 0; i < 4; ++i) {
            #pragma unroll
            for (int r = 0; r < 4; ++r) {
                int row = 64 * wm + 16 * i + 4 * lq + r;
                int n = n00 + row;
                float c0v, s0v, c1v, s1v;
                sincosf((float)n * f0, &s0v, &c0v);
                sincosf((float)n * f1, &s1v, &c1v);
                float q0 = acc[i][0][r], q1 = acc[i][1][r];
                float q2 = acc[i][2][r], q3 = acc[i][3][r];
                u.Css[row][64 * wn + lr]      = f2b(q0 * c0v - q2 * s0v);
                u.Css[row][64 * wn + 16 + lr] = f2b(q1 * c1v - q3 * s1v);
                u.Css[row][64 * wn + 32 + lr] = f2b(q2 * c0v + q0 * s0v);
                u.Css[row][64 * wn + 48 + lr] = f2b(q3 * c1v + q1 * s1v);
            }
        }
        __syncthreads();
        int row = tid >> 1, hh = tid & 1;
        int h = (e00 >> 6) + hh;
        int n = n00 + row;
        size_t base = (((size_t)(b * NH + h)) * SEQ + n) * HD;
        #pragma unroll
        for (int p = 0; p < 8; ++p)
            *(v8s*)&K[base + 8 * p] = *(const v8s*)&u.Css[row][64 * hh + 8 * p];
    } else {
        // V transposed: Css_T[col][row], packed b64 along row (r contiguous)
        #pragma unroll
        for (int i = 0; i < 4; ++i) {
            #pragma unroll
            for (int j = 0; j < 4; ++j) {
                v4s t;
                #pragma unroll
                for (int r = 0; r < 4; ++r) t[r] = f2b(acc[i][j][r]);
                *(v4s*)&u.Css[64 * wn + 16 * j + lr][64 * wm + 16 * i + 4 * lq] = t;
            }
        }
        __syncthreads();
        int c = tid >> 1, half = (tid & 1) * 64;
        int h = (e00 + c) >> 6, d = (e00 + c) & 63;
        size_t base = (((size_t)(b * NH + h)) * HD + d) * SEQ + n00 + half;
        #pragma unroll
        for (int p = 0; p < 8; ++p)
            *(v8s*)&Vt[base + 8 * p] = *(const v8s*)&u.Css[c][half + 8 * p];
    }
}

// ---------------------------------------------------------------------------
// Kernel 2: fused Q-proj + RoPE + flash attention, 128-row Q-tile.
// Fixed-max softmax (M=24 folded into mask bias). Key-permuted K staging so
// P is written as packed v4s (key(nt,lr) = 4*lr+nt). K/V fragments hoisted
// to registers once per chunk; next chunk's K/V/mask register-prefetched.
// grid = (MTOT/128, NH) = 512 blocks (2/CU). launch_bounds(256,2): ~256 VGPR.
// ---------------------------------------------------------------------------
__global__ __launch_bounds__(256, 2) void attn_mfma(
    const short* __restrict__ xb, const short* __restrict__ Wqb,
    const short* __restrict__ K, const short* __restrict__ Vt,
    const int* __restrict__ mask, short* __restrict__ O)
{
    const int m0 = blockIdx.x * 128, h = blockIdx.y, e0 = h * 64;
    const int b = m0 >> 11, n0 = m0 & (SEQ - 1), bh = b * NH + h;
    const int tid = threadIdx.x;
    const int w = tid >> 6, lane = tid & 63, lq = lane >> 4, lr = lane & 15;
    const int sr = tid >> 2, sc = (tid & 3) * 8;

    __shared__ union {
        struct { short As[128][32]; short Bs[64][32]; } p1;   // 12 KB
        struct { short Ks[64][72]; short Vs[64][72]; } p2;    // 18.4 KB
    } u;
    __shared__ short Ps[128][72];                             // 18.4 KB
    __shared__ float mbias[64];

    // ---- Phase 1: Q[128][64] = x_tile @ Wq_h^T ----
    v4f acc[2][4];
    #pragma unroll
    for (int s = 0; s < 2; ++s)
        for (int nt = 0; nt < 4; ++nt)
            for (int r = 0; r < 4; ++r) acc[s][nt][r] = 0.f;

    for (int k0 = 0; k0 < DM; k0 += 32) {
        v8s a0 = *(const v8s*)&xb[(size_t)(m0 + sr) * DM + k0 + sc];
        v8s a1 = *(const v8s*)&xb[(size_t)(m0 + 64 + sr) * DM + k0 + sc];
        v8s bv = *(const v8s*)&Wqb[(size_t)(e0 + sr) * DM + k0 + sc];
        __syncthreads();
        *(v8s*)&u.p1.As[sr][sc] = a0;
        *(v8s*)&u.p1.As[64 + sr][sc] = a1;
        *(v8s*)&u.p1.Bs[sr][sc] = bv;
        __syncthreads();
        v8s aw0 = *(const v8s*)&u.p1.As[16 * w + lr][lq * 8];
        v8s aw1 = *(const v8s*)&u.p1.As[64 + 16 * w + lr][lq * 8];
        #pragma unroll
        for (int nt = 0; nt < 4; ++nt) {
            v8s bb = *(const v8s*)&u.p1.Bs[16 * nt + lr][lq * 8];
            acc[0][nt] = MFMA16(aw0, bb, acc[0][nt]);
            acc[1][nt] = MFMA16(aw1, bb, acc[1][nt]);
        }
    }

    // ---- RoPE in registers (pair nt <-> nt^2 is j <-> j^32), fold scale ----
    // Ps rows written/read wave-private: no barrier needed around them.
    {
        const float LN1E4_D32 = 0.28782313662425572f;
        const float QSCALE = 0.18033688011112042f;   // 0.125 * log2(e)
        float f0 = expf(-(float)lr * LN1E4_D32);          // jj = lr
        float f1 = expf(-(float)(16 + lr) * LN1E4_D32);   // jj = 16+lr
        #pragma unroll
        for (int s = 0; s < 2; ++s) {
            #pragma unroll
            for (int r = 0; r < 4; ++r) {
                int n = n0 + 64 * s + 16 * w + 4 * lq + r;
                float c0v, s0v, c1v, s1v;
                sincosf((float)n * f0, &s0v, &c0v);
                sincosf((float)n * f1, &s1v, &c1v);
                float q0 = acc[s][0][r], q1 = acc[s][1][r];
                float q2 = acc[s][2][r], q3 = acc[s][3][r];
                Ps[64 * s + 16 * w + 4 * lq + r][lr]      = f2b(QSCALE * (q0 * c0v - q2 * s0v));
                Ps[64 * s + 16 * w + 4 * lq + r][16 + lr] = f2b(QSCALE * (q1 * c1v - q3 * s1v));
                Ps[64 * s + 16 * w + 4 * lq + r][32 + lr] = f2b(QSCALE * (q2 * c0v + q0 * s0v));
                Ps[64 * s + 16 * w + 4 * lq + r][48 + lr] = f2b(QSCALE * (q3 * c1v + q1 * s1v));
            }
        }
    }
    v8s aq[2][2];                                  // Q A-fragments, wave-private
    #pragma unroll
    for (int s = 0; s < 2; ++s)
        #pragma unroll
        for (int ks = 0; ks < 2; ++ks)
            aq[s][ks] = *(const v8s*)&Ps[64 * s + 16 * w + lr][32 * ks + 8 * lq];

    // ---- Phase 2: flash loop, fixed-max softmax (M = 24 in log2 domain) ----
    float lacc[2][4];
    #pragma unroll
    for (int s = 0; s < 2; ++s)
        for (int r = 0; r < 4; ++r) lacc[s][r] = 0.f;
    v4f o[2][4];
    #pragma unroll
    for (int s = 0; s < 2; ++s)
        for (int nt = 0; nt < 4; ++nt)
            for (int r = 0; r < 4; ++r) o[s][nt][r] = 0.f;

    const int r2 = tid >> 2, cc = (tid & 3) * 16;
    const int pr = 16 * (r2 & 3) + (r2 >> 2);      // permuted K row
    const short* __restrict__ Kb = K + (size_t)bh * SEQ * HD;
    const short* __restrict__ Vb = Vt + (size_t)bh * HD * SEQ;

    // prefetch chunk 0
    v8s k1 = *(const v8s*)&Kb[(size_t)r2 * HD + cc];
    v8s k2 = *(const v8s*)&Kb[(size_t)r2 * HD + cc + 8];
    v8s v1 = *(const v8s*)&Vb[(size_t)r2 * SEQ + cc];
    v8s v2 = *(const v8s*)&Vb[(size_t)r2 * SEQ + cc + 8];
    int mnext = (tid < 64) ? mask[b * SEQ + tid] : 0;

    for (int c0 = 0; c0 < SEQ; c0 += 64) {
        __syncthreads();                      // prev chunk LDS reads done
        *(v8s*)&u.p2.Ks[pr][cc] = k1;         // key-permuted rows
        *(v8s*)&u.p2.Ks[pr][cc + 8] = k2;
        *(v8s*)&u.p2.Vs[r2][cc] = v1;
        *(v8s*)&u.p2.Vs[r2][cc + 8] = v2;
        if (tid < 64) mbias[tid] = mnext ? -24.0f : -1e30f;
        __syncthreads();
        if (c0 + 64 < SEQ) {                  // prefetch next chunk
            k1 = *(const v8s*)&Kb[(size_t)(c0 + 64 + r2) * HD + cc];
            k2 = *(const v8s*)&Kb[(size_t)(c0 + 64 + r2) * HD + cc + 8];
            v1 = *(const v8s*)&Vb[(size_t)r2 * SEQ + c0 + 64 + cc];
            v2 = *(const v8s*)&Vb[(size_t)r2 * SEQ + c0 + 64 + cc + 8];
            if (tid < 64) mnext = mask[b * SEQ + c0 + 64 + tid];
        }

        // hoist K/V fragments to registers (used by both q-strips)
        v8s kf[2][4], vf[2][4];
        #pragma unroll
        for (int ks = 0; ks < 2; ++ks)
            #pragma unroll
            for (int nt = 0; nt < 4; ++nt) {
                kf[ks][nt] = *(const v8s*)&u.p2.Ks[16 * nt + lr][32 * ks + 8 * lq];
                vf[ks][nt] = *(const v8s*)&u.p2.Vs[16 * nt + lr][32 * ks + 8 * lq];
            }
        float bias[4];
        #pragma unroll
        for (int nt = 0; nt < 4; ++nt) bias[nt] = mbias[4 * lr + nt];

        #pragma unroll
        for (int s = 0; s < 2; ++s) {
            // S = Q @ K^T ; output col (nt,lr) <-> key 4*lr+nt (permuted K)
            v4f sv[4];
            #pragma unroll
            for (int nt = 0; nt < 4; ++nt)
                for (int r = 0; r < 4; ++r) sv[nt][r] = 0.f;
            #pragma unroll
            for (int ks = 0; ks < 2; ++ks)
                #pragma unroll
                for (int nt = 0; nt < 4; ++nt)
                    sv[nt] = MFMA16(aq[s][ks], kf[ks][nt], sv[nt]);

            // p = exp2(s + bias); packed v4s write (keys 4lr..4lr+3)
            #pragma unroll
            for (int r = 0; r < 4; ++r) {
                v4s pk;
                #pragma unroll
                for (int nt = 0; nt < 4; ++nt) {
                    float p = exp2f(sv[nt][r] + bias[nt]);
                    lacc[s][r] += p;
                    pk[nt] = f2b(p);
                }
                *(v4s*)&Ps[64 * s + 16 * w + 4 * lq + r][4 * lr] = pk;
            }
            // O += P @ V  (Ps row-strip wave-private; cols = natural keys)
            #pragma unroll
            for (int ks = 0; ks < 2; ++ks) {
                v8s a = *(const v8s*)&Ps[64 * s + 16 * w + lr][32 * ks + 8 * lq];
                #pragma unroll
                for (int nt = 0; nt < 4; ++nt)
                    o[s][nt] = MFMA16(a, vf[ks][nt], o[s][nt]);
            }
        }
    }

    // ---- finalize: one butterfly per row; all-masked rows -> l=0 -> 0 ----
    #pragma unroll
    for (int s = 0; s < 2; ++s) {
        #pragma unroll
        for (int r = 0; r < 4; ++r) {
            float l = lacc[s][r];
            l += __shfl_xor(l, 1);
            l += __shfl_xor(l, 2);
            l += __shfl_xor(l, 4);
            l += __shfl_xor(l, 8);
            float inv = (l > 0.f) ? 1.f / l : 0.f;
            int qrow = 64 * s + 16 * w + 4 * lq + r;
            #pragma unroll
            for (int nt = 0; nt < 4; ++nt)
                O[(size_t)(m0 + qrow) * DM + h * HD + 16 * nt + lr] =
                    f2b(o[s][nt][r] * inv);
        }
    }
}

// ---------------------------------------------------------------------------
// Kernel 3: out = O @ Wo^T, 64x128 MFMA tile (512 blocks -> 2/CU), fp32 store.
// grid = (MTOT/64, DM/128). Wave w owns col-strip 32w (2 n-tiles), 4 m-tiles.
// ---------------------------------------------------------------------------
__global__ __launch_bounds__(256, 2) void oproj_mfma(
    const short* __restrict__ O, const short* __restrict__ Wob,
    float* __restrict__ out)
{
    const int m0 = blockIdx.x * 64, e00 = blockIdx.y * 128;
    const int tid = threadIdx.x;
    const int w = tid >> 6, lane = tid & 63, lq = lane >> 4, lr = lane & 15;

    __shared__ short As[64][32];    // 4 KB
    __shared__ short Bs[128][32];   // 8 KB

    v4f acc[4][2];
    #pragma unroll
    for (int i = 0; i < 4; ++i)
        for (int j = 0; j < 2; ++j)
            for (int r = 0; r < 4; ++r) acc[i][j][r] = 0.f;

    const int arow = tid >> 2, aseg = (tid & 3) * 8;
    const int brow = tid >> 1, bseg = (tid & 1) * 16;
    for (int k0 = 0; k0 < DM; k0 += 32) {
        v8s a0 = *(const v8s*)&O[(size_t)(m0 + arow) * DM + k0 + aseg];
        v8s b0 = *(const v8s*)&Wob[(size_t)(e00 + brow) * DM + k0 + bseg];
        v8s b1 = *(const v8s*)&Wob[(size_t)(e00 + brow) * DM + k0 + bseg + 8];
        __syncthreads();
        *(v8s*)&As[arow][aseg] = a0;
        *(v8s*)&Bs[brow][bseg] = b0;
        *(v8s*)&Bs[brow][bseg + 8] = b1;
        __syncthreads();
        v8s af[4], bf[2];
        #pragma unroll
        for (int i = 0; i < 4; ++i)
            af[i] = *(const v8s*)&As[16 * i + lr][8 * lq];
        #pragma unroll
        for (int j = 0; j < 2; ++j)
            bf[j] = *(const v8s*)&Bs[32 * w + 16 * j + lr][8 * lq];
        #pragma unroll
        for (int i = 0; i < 4; ++i)
            #pragma unroll
            for (int j = 0; j < 2; ++j)
                acc[i][j] = MFMA16(af[i], bf[j], acc[i][j]);
    }

    #pragma unroll
    for (int i = 0; i < 4; ++i)
        #pragma unroll
        for (int r = 0; r < 4; ++r) {
            int m = m0 + 16 * i + 4 * lq + r;
            #pragma unroll
            for (int j = 0; j < 2; ++j)
                out[(size_t)m * DM + e00 + 32 * w + 16 * j + lr] = acc[i][j][r];
        }
}

// ---------------------------------------------------------------------------
extern "C" void kernel_launch(void* const* d_in, const int* in_sizes, int n_in,
                              void* d_out, int out_size, void* d_ws, size_t ws_size,
                              hipStream_t stream)
{
    const float* x    = (const float*)d_in[0];
    const int*   mask = (const int*)d_in[1];
    const float* Wq   = (const float*)d_in[2];
    const float* Wk   = (const float*)d_in[3];
    const float* Wv   = (const float*)d_in[4];
    const float* Wo   = (const float*)d_in[5];
    float* out = (float*)d_out;

    // ws (24 MiB of shorts): xb | Wqb | Wkb | Wvb | Wob | O  (first 5 contiguous
    // regions are filled by the single cvt_all kernel)
    short* xb  = (short*)d_ws;                    // 4 Mi
    short* Wqb = xb  + (size_t)MTOT * DM;         // 1 Mi each
    short* Wkb = Wqb + (size_t)DM * DM;
    short* Wvb = Wkb + (size_t)DM * DM;
    short* Wob = Wvb + (size_t)DM * DM;
    short* O   = Wob + (size_t)DM * DM;           // 4 Mi
    // d_out (16 MiB) doubles as K/Vt scratch until the final projection
    short* K  = (short*)d_out;                    // 4 Mi
    short* Vt = K + (size_t)MTOT * DM;            // 4 Mi

    cvt_all_kernel<<<4096, 256, 0, stream>>>(x, Wq, Wk, Wv, Wo, xb);

    dim3 g1(MTOT / 128, DM / 128, 2);
    kv_rope_mfma<<<g1, 256, 0, stream>>>(xb, Wkb, Wvb, K, Vt);

    dim3 g2(MTOT / 128, NH);
    attn_mfma<<<g2, 256, 0, stream>>>(xb, Wqb, K, Vt, mask, O);

    dim3 g3(MTOT / 64, DM / 128);
    oproj_mfma<<<g3, 256, 0, stream>>>(O, Wob, out);
}

// Round 10
// 218.934 us; speedup vs baseline: 2.1613x; 1.0131x over previous
//
#include <hip/hip_runtime.h>
#include <math.h>

#define BATCH 2
#define SEQ   2048
#define DM    1024
#define NH    16
#define HD    64
#define MTOT  (BATCH*SEQ)            // 4096

typedef short v8s __attribute__((ext_vector_type(8)));   // 8 bf16 = 4 VGPR
typedef short v4s __attribute__((ext_vector_type(4)));
typedef float v4f __attribute__((ext_vector_type(4)));

#define MFMA16(a, b, c) __builtin_amdgcn_mfma_f32_16x16x32_bf16((a), (b), (c), 0, 0, 0)

__device__ __forceinline__ short f2b(float f) {   // fp32->bf16, round-half-up
    union { float f; unsigned u; } v; v.f = f;
    return (short)((v.u + 0x8000u) >> 16);
}

// native RoPE sincos: angle = n * inv_freq (radians), computed via revolutions
// + fract + v_sin/v_cos (no library range-reduction). f_rev = inv_freq/(2pi).
__device__ __forceinline__ void rope_cs(int n, float f_rev, float* c, float* s) {
    float rev = (float)n * f_rev;
    float t = rev - floorf(rev);
    float ang = t * 6.283185307179586f;
    *c = __cosf(ang);
    *s = __sinf(ang);
}

#define L2_1E4_D32 0.4152410118609203f   // log2(10000)/32
#define INV2PI     0.15915494309189535f

// ---------------------------------------------------------------------------
// Kernel 0: fused fp32 -> bf16 convert for x | Wq | Wk | Wv | Wo into ws base.
// ---------------------------------------------------------------------------
__global__ __launch_bounds__(256) void cvt_all_kernel(
    const float* __restrict__ x,  const float* __restrict__ wq,
    const float* __restrict__ wk, const float* __restrict__ wv,
    const float* __restrict__ wo, short* __restrict__ dst)
{
    int i = blockIdx.x * 256 + threadIdx.x;            // < 1 Mi
    const float* src; int off;
    if (i < (1 << 19)) { src = x; off = i; }
    else {
        int j = i - (1 << 19);
        int wsel = j >> 17;
        off = j & ((1 << 17) - 1);
        src = (wsel == 0) ? wq : (wsel == 1) ? wk : (wsel == 2) ? wv : wo;
    }
    const float4* s4 = (const float4*)src;
    float4 a = s4[2 * off], b = s4[2 * off + 1];
    v8s p;
    p[0] = f2b(a.x); p[1] = f2b(a.y); p[2] = f2b(a.z); p[3] = f2b(a.w);
    p[4] = f2b(b.x); p[5] = f2b(b.y); p[6] = f2b(b.z); p[7] = f2b(b.w);
    *(v8s*)&dst[8 * i] = p;
}

// ---------------------------------------------------------------------------
// Kernel 1: K/V projections, 128x128 MFMA tile. Native-sincos RoPE.
//   z=0: K = RoPE(x @ Wk^T) -> [bh][key][d]
//   z=1: V = x @ Wv^T -> Vt[bh][d][key]   (transposed via LDS)
// grid = (MTOT/128, DM/128, 2).
// ---------------------------------------------------------------------------
__global__ __launch_bounds__(256, 2) void kv_rope_mfma(
    const short* __restrict__ xb, const short* __restrict__ Wkb,
    const short* __restrict__ Wvb, short* __restrict__ K, short* __restrict__ Vt)
{
    const int zz = blockIdx.z;
    const short* __restrict__ Wb = zz ? Wvb : Wkb;
    const int m0 = blockIdx.x * 128, e00 = blockIdx.y * 128;
    const int tid = threadIdx.x;
    const int w = tid >> 6, lane = tid & 63, lq = lane >> 4, lr = lane & 15;
    const int wm = w >> 1, wn = w & 1;

    __shared__ union {
        struct { short As[128][32]; short Bs[128][32]; } p1;  // 16 KB
        short Css[128][136];                                   // 34 KB
    } u;

    v4f acc[4][4];
    #pragma unroll
    for (int i = 0; i < 4; ++i)
        for (int j = 0; j < 4; ++j)
            for (int r = 0; r < 4; ++r) acc[i][j][r] = 0.f;

    const int arow = tid >> 1, aseg = (tid & 1) * 16;
    for (int k0 = 0; k0 < DM; k0 += 32) {
        v8s a0 = *(const v8s*)&xb[(size_t)(m0 + arow) * DM + k0 + aseg];
        v8s a1 = *(const v8s*)&xb[(size_t)(m0 + arow) * DM + k0 + aseg + 8];
        v8s b0 = *(const v8s*)&Wb[(size_t)(e00 + arow) * DM + k0 + aseg];
        v8s b1 = *(const v8s*)&Wb[(size_t)(e00 + arow) * DM + k0 + aseg + 8];
        __syncthreads();
        *(v8s*)&u.p1.As[arow][aseg] = a0;
        *(v8s*)&u.p1.As[arow][aseg + 8] = a1;
        *(v8s*)&u.p1.Bs[arow][aseg] = b0;
        *(v8s*)&u.p1.Bs[arow][aseg + 8] = b1;
        __syncthreads();
        v8s af[4], bf[4];
        #pragma unroll
        for (int i = 0; i < 4; ++i)
            af[i] = *(const v8s*)&u.p1.As[64 * wm + 16 * i + lr][8 * lq];
        #pragma unroll
        for (int j = 0; j < 4; ++j)
            bf[j] = *(const v8s*)&u.p1.Bs[64 * wn + 16 * j + lr][8 * lq];
        #pragma unroll
        for (int i = 0; i < 4; ++i)
            #pragma unroll
            for (int j = 0; j < 4; ++j)
                acc[i][j] = MFMA16(af[i], bf[j], acc[i][j]);
    }
    __syncthreads();   // k-loop LDS reads done before Css overwrite

    const int b = m0 >> 11, n00 = m0 & (SEQ - 1);

    if (zz == 0) {
        // RoPE in-register (cols of this wave = one head; pairs nt <-> nt^2)
        float f0 = exp2f(-(float)lr * L2_1E4_D32) * INV2PI;
        float f1 = exp2f(-(float)(16 + lr) * L2_1E4_D32) * INV2PI;
        #pragma unroll
        for (int i = 0; i < 4; ++i) {
            #pragma unroll
            for (int r = 0; r < 4; ++r) {
                int row = 64 * wm + 16 * i + 4 * lq + r;
                int n = n00 + row;
                float c0v, s0v, c1v, s1v;
                rope_cs(n, f0, &c0v, &s0v);
                rope_cs(n, f1, &c1v, &s1v);
                float q0 = acc[i][0][r], q1 = acc[i][1][r];
                float q2 = acc[i][2][r], q3 = acc[i][3][r];
                u.Css[row][64 * wn + lr]      = f2b(q0 * c0v - q2 * s0v);
                u.Css[row][64 * wn + 16 + lr] = f2b(q1 * c1v - q3 * s1v);
                u.Css[row][64 * wn + 32 + lr] = f2b(q2 * c0v + q0 * s0v);
                u.Css[row][64 * wn + 48 + lr] = f2b(q3 * c1v + q1 * s1v);
            }
        }
        __syncthreads();
        int row = tid >> 1, hh = tid & 1;
        int h = (e00 >> 6) + hh;
        int n = n00 + row;
        size_t base = (((size_t)(b * NH + h)) * SEQ + n) * HD;
        #pragma unroll
        for (int p = 0; p < 8; ++p)
            *(v8s*)&K[base + 8 * p] = *(const v8s*)&u.Css[row][64 * hh + 8 * p];
    } else {
        // V transposed: Css_T[col][row], packed b64 along row (r contiguous)
        #pragma unroll
        for (int i = 0; i < 4; ++i) {
            #pragma unroll
            for (int j = 0; j < 4; ++j) {
                v4s t;
                #pragma unroll
                for (int r = 0; r < 4; ++r) t[r] = f2b(acc[i][j][r]);
                *(v4s*)&u.Css[64 * wn + 16 * j + lr][64 * wm + 16 * i + 4 * lq] = t;
            }
        }
        __syncthreads();
        int c = tid >> 1, half = (tid & 1) * 64;
        int h = (e00 + c) >> 6, d = (e00 + c) & 63;
        size_t base = (((size_t)(b * NH + h)) * HD + d) * SEQ + n00 + half;
        #pragma unroll
        for (int p = 0; p < 8; ++p)
            *(v8s*)&Vt[base + 8 * p] = *(const v8s*)&u.Css[c][half + 8 * p];
    }
}

// ---------------------------------------------------------------------------
// Kernel 2: fused Q-proj + RoPE + flash attention. 128-row Q-tile, 512 thr /
// 8 waves (one 16-row strip each) -> 16 waves/CU at 2 blocks/CU (2x R9).
// Fixed-max softmax (M=24 in mask bias), key-permuted K staging (packed v4s
// P-writes), K/V fragments hoisted, register prefetch, native-sincos RoPE.
// grid = (MTOT/128, NH) = 512 blocks.
// ---------------------------------------------------------------------------
__global__ __launch_bounds__(512, 4) void attn_mfma(
    const short* __restrict__ xb, const short* __restrict__ Wqb,
    const short* __restrict__ K, const short* __restrict__ Vt,
    const int* __restrict__ mask, short* __restrict__ O)
{
    const int m0 = blockIdx.x * 128, h = blockIdx.y, e0 = h * 64;
    const int b = m0 >> 11, n0 = m0 & (SEQ - 1), bh = b * NH + h;
    const int tid = threadIdx.x;
    const int w = tid >> 6, lane = tid & 63, lq = lane >> 4, lr = lane & 15;

    __shared__ union {
        struct { short As[128][32]; short Bs[64][32]; } p1;   // 12 KB
        struct { short Ks[64][72]; short Vs[64][72]; } p2;    // 18.4 KB
    } u;
    __shared__ short Ps[128][72];                             // 18.4 KB
    __shared__ float mbias[64];

    // ---- Phase 1: Q[128][64] = x_tile @ Wq_h^T (8 waves, 1 strip each) ----
    v4f acc[4];
    #pragma unroll
    for (int nt = 0; nt < 4; ++nt)
        for (int r = 0; r < 4; ++r) acc[nt][r] = 0.f;

    const int sr = tid >> 2, sc = (tid & 3) * 8;              // A: 128 rows
    const int br = (tid - 256) >> 2, bc = (tid & 3) * 8;      // B: 64 rows
    for (int k0 = 0; k0 < DM; k0 += 32) {
        v8s a0 = *(const v8s*)&xb[(size_t)(m0 + sr) * DM + k0 + sc];
        v8s bv;
        if (tid >= 256)
            bv = *(const v8s*)&Wqb[(size_t)(e0 + br) * DM + k0 + bc];
        __syncthreads();
        *(v8s*)&u.p1.As[sr][sc] = a0;
        if (tid >= 256)
            *(v8s*)&u.p1.Bs[br][bc] = bv;
        __syncthreads();
        v8s aw = *(const v8s*)&u.p1.As[16 * w + lr][8 * lq];
        #pragma unroll
        for (int nt = 0; nt < 4; ++nt) {
            v8s bb = *(const v8s*)&u.p1.Bs[16 * nt + lr][8 * lq];
            acc[nt] = MFMA16(aw, bb, acc[nt]);
        }
    }

    // ---- RoPE in registers (pair nt <-> nt^2 is j <-> j^32), fold scale ----
    {
        const float QSCALE = 0.18033688011112042f;   // 0.125 * log2(e)
        float f0 = exp2f(-(float)lr * L2_1E4_D32) * INV2PI;
        float f1 = exp2f(-(float)(16 + lr) * L2_1E4_D32) * INV2PI;
        #pragma unroll
        for (int r = 0; r < 4; ++r) {
            int row = 16 * w + 4 * lq + r;
            int n = n0 + row;
            float c0v, s0v, c1v, s1v;
            rope_cs(n, f0, &c0v, &s0v);
            rope_cs(n, f1, &c1v, &s1v);
            float q0 = acc[0][r], q1 = acc[1][r];
            float q2 = acc[2][r], q3 = acc[3][r];
            Ps[row][lr]      = f2b(QSCALE * (q0 * c0v - q2 * s0v));
            Ps[row][16 + lr] = f2b(QSCALE * (q1 * c1v - q3 * s1v));
            Ps[row][32 + lr] = f2b(QSCALE * (q2 * c0v + q0 * s0v));
            Ps[row][48 + lr] = f2b(QSCALE * (q3 * c1v + q1 * s1v));
        }
    }
    // wave-private rows: intra-wave LDS ordering suffices (no barrier)
    v8s aq[2];
    #pragma unroll
    for (int ks = 0; ks < 2; ++ks)
        aq[ks] = *(const v8s*)&Ps[16 * w + lr][32 * ks + 8 * lq];

    // ---- Phase 2: flash loop, fixed-max softmax (M = 24, log2 domain) ----
    float lacc[4] = {0.f, 0.f, 0.f, 0.f};
    v4f o[4];
    #pragma unroll
    for (int nt = 0; nt < 4; ++nt)
        for (int r = 0; r < 4; ++r) o[nt][r] = 0.f;

    const int kr = tid >> 3, kc = (tid & 7) * 8;   // 64 rows x 64 cols, 8/thread
    const int pr = 16 * (kr & 3) + (kr >> 2);      // permuted K row
    const short* __restrict__ Kb = K + (size_t)bh * SEQ * HD;
    const short* __restrict__ Vb = Vt + (size_t)bh * HD * SEQ;

    // prefetch chunk 0
    v8s k1 = *(const v8s*)&Kb[(size_t)kr * HD + kc];
    v8s v1 = *(const v8s*)&Vb[(size_t)kr * SEQ + kc];
    int mnext = (tid < 64) ? mask[b * SEQ + tid] : 0;

    for (int c0 = 0; c0 < SEQ; c0 += 64) {
        __syncthreads();                      // prev chunk LDS reads done
        *(v8s*)&u.p2.Ks[pr][kc] = k1;         // key-permuted rows
        *(v8s*)&u.p2.Vs[kr][kc] = v1;         // [d][key]
        if (tid < 64) mbias[tid] = mnext ? -24.0f : -1e30f;
        __syncthreads();
        if (c0 + 64 < SEQ) {                  // prefetch next chunk
            k1 = *(const v8s*)&Kb[(size_t)(c0 + 64 + kr) * HD + kc];
            v1 = *(const v8s*)&Vb[(size_t)kr * SEQ + c0 + 64 + kc];
            if (tid < 64) mnext = mask[b * SEQ + c0 + 64 + tid];
        }

        // hoist K/V fragments to registers
        v8s kf[2][4], vf[2][4];
        #pragma unroll
        for (int ks = 0; ks < 2; ++ks)
            #pragma unroll
            for (int nt = 0; nt < 4; ++nt) {
                kf[ks][nt] = *(const v8s*)&u.p2.Ks[16 * nt + lr][32 * ks + 8 * lq];
                vf[ks][nt] = *(const v8s*)&u.p2.Vs[16 * nt + lr][32 * ks + 8 * lq];
            }
        float bias[4];
        #pragma unroll
        for (int nt = 0; nt < 4; ++nt) bias[nt] = mbias[4 * lr + nt];

        // S = Q @ K^T ; output col (nt,lr) <-> key 4*lr+nt (permuted K)
        v4f sv[4];
        #pragma unroll
        for (int nt = 0; nt < 4; ++nt)
            for (int r = 0; r < 4; ++r) sv[nt][r] = 0.f;
        #pragma unroll
        for (int ks = 0; ks < 2; ++ks)
            #pragma unroll
            for (int nt = 0; nt < 4; ++nt)
                sv[nt] = MFMA16(aq[ks], kf[ks][nt], sv[nt]);

        // p = exp2(s + bias); packed v4s write (keys 4lr..4lr+3)
        #pragma unroll
        for (int r = 0; r < 4; ++r) {
            v4s pk;
            #pragma unroll
            for (int nt = 0; nt < 4; ++nt) {
                float p = exp2f(sv[nt][r] + bias[nt]);
                lacc[r] += p;
                pk[nt] = f2b(p);
            }
            *(v4s*)&Ps[16 * w + 4 * lq + r][4 * lr] = pk;
        }
        // O += P @ V  (Ps row-strip wave-private; cols = natural keys)
        #pragma unroll
        for (int ks = 0; ks < 2; ++ks) {
            v8s a = *(const v8s*)&Ps[16 * w + lr][32 * ks + 8 * lq];
            #pragma unroll
            for (int nt = 0; nt < 4; ++nt)
                o[nt] = MFMA16(a, vf[ks][nt], o[nt]);
        }
    }

    // ---- finalize: one butterfly per row; all-masked rows -> l=0 -> 0 ----
    #pragma unroll
    for (int r = 0; r < 4; ++r) {
        float l = lacc[r];
        l += __shfl_xor(l, 1);
        l += __shfl_xor(l, 2);
        l += __shfl_xor(l, 4);
        l += __shfl_xor(l, 8);
        float inv = (l > 0.f) ? 1.f / l : 0.f;
        int qrow = 16 * w + 4 * lq + r;
        #pragma unroll
        for (int nt = 0; nt < 4; ++nt)
            O[(size_t)(m0 + qrow) * DM + h * HD + 16 * nt + lr] =
                f2b(o[nt][r] * inv);
    }
}

// ---------------------------------------------------------------------------
// Kernel 3: out = O @ Wo^T, 64x128 MFMA tile (512 blocks), fp32 store.
// grid = (MTOT/64, DM/128).
// ---------------------------------------------------------------------------
__global__ __launch_bounds__(256, 2) void oproj_mfma(
    const short* __restrict__ O, const short* __restrict__ Wob,
    float* __restrict__ out)
{
    const int m0 = blockIdx.x * 64, e00 = blockIdx.y * 128;
    const int tid = threadIdx.x;
    const int w = tid >> 6, lane = tid & 63, lq = lane >> 4, lr = lane & 15;

    __shared__ short As[64][32];    // 4 KB
    __shared__ short Bs[128][32];   // 8 KB

    v4f acc[4][2];
    #pragma unroll
    for (int i = 0; i < 4; ++i)
        for (int j = 0; j < 2; ++j)
            for (int r = 0; r < 4; ++r) acc[i][j][r] = 0.f;

    const int arow = tid >> 2, aseg = (tid & 3) * 8;
    const int brow = tid >> 1, bseg = (tid & 1) * 16;
    for (int k0 = 0; k0 < DM; k0 += 32) {
        v8s a0 = *(const v8s*)&O[(size_t)(m0 + arow) * DM + k0 + aseg];
        v8s b0 = *(const v8s*)&Wob[(size_t)(e00 + brow) * DM + k0 + bseg];
        v8s b1 = *(const v8s*)&Wob[(size_t)(e00 + brow) * DM + k0 + bseg + 8];
        __syncthreads();
        *(v8s*)&As[arow][aseg] = a0;
        *(v8s*)&Bs[brow][bseg] = b0;
        *(v8s*)&Bs[brow][bseg + 8] = b1;
        __syncthreads();
        v8s af[4], bf[2];
        #pragma unroll
        for (int i = 0; i < 4; ++i)
            af[i] = *(const v8s*)&As[16 * i + lr][8 * lq];
        #pragma unroll
        for (int j = 0; j < 2; ++j)
            bf[j] = *(const v8s*)&Bs[32 * w + 16 * j + lr][8 * lq];
        #pragma unroll
        for (int i = 0; i < 4; ++i)
            #pragma unroll
            for (int j = 0; j < 2; ++j)
                acc[i][j] = MFMA16(af[i], bf[j], acc[i][j]);
    }

    #pragma unroll
    for (int i = 0; i < 4; ++i)
        #pragma unroll
        for (int r = 0; r < 4; ++r) {
            int m = m0 + 16 * i + 4 * lq + r;
            #pragma unroll
            for (int j = 0; j < 2; ++j)
                out[(size_t)m * DM + e00 + 32 * w + 16 * j + lr] = acc[i][j][r];
        }
}

// ---------------------------------------------------------------------------
extern "C" void kernel_launch(void* const* d_in, const int* in_sizes, int n_in,
                              void* d_out, int out_size, void* d_ws, size_t ws_size,
                              hipStream_t stream)
{
    const float* x    = (const float*)d_in[0];
    const int*   mask = (const int*)d_in[1];
    const float* Wq   = (const float*)d_in[2];
    const float* Wk   = (const float*)d_in[3];
    const float* Wv   = (const float*)d_in[4];
    const float* Wo   = (const float*)d_in[5];
    float* out = (float*)d_out;

    // ws (24 MiB of shorts): xb | Wqb | Wkb | Wvb | Wob | O
    short* xb  = (short*)d_ws;                    // 8 MB
    short* Wqb = xb  + (size_t)MTOT * DM;         // 2 MB each
    short* Wkb = Wqb + (size_t)DM * DM;
    short* Wvb = Wkb + (size_t)DM * DM;
    short* Wob = Wvb + (size_t)DM * DM;
    short* O   = Wob + (size_t)DM * DM;           // 8 MB
    // d_out (16 MiB) doubles as K/Vt scratch until the final projection
    short* K  = (short*)d_out;                    // 8 MB
    short* Vt = K + (size_t)MTOT * DM;            // 8 MB

    cvt_all_kernel<<<4096, 256, 0, stream>>>(x, Wq, Wk, Wv, Wo, xb);

    dim3 g1(MTOT / 128, DM / 128, 2);
    kv_rope_mfma<<<g1, 256, 0, stream>>>(xb, Wkb, Wvb, K, Vt);

    dim3 g2(MTOT / 128, NH);
    attn_mfma<<<g2, 512, 0, stream>>>(xb, Wqb, K, Vt, mask, O);

    dim3 g3(MTOT / 64, DM / 128);
    oproj_mfma<<<g3, 256, 0, stream>>>(O, Wob, out);
}

// Round 11
// 211.645 us; speedup vs baseline: 2.2357x; 1.0344x over previous
//
#include <hip/hip_runtime.h>
#include <math.h>

#define BATCH 2
#define SEQ   2048
#define DM    1024
#define NH    16
#define HD    64
#define MTOT  (BATCH*SEQ)            // 4096

typedef short v8s __attribute__((ext_vector_type(8)));   // 8 bf16 = 4 VGPR
typedef short v4s __attribute__((ext_vector_type(4)));
typedef float v4f __attribute__((ext_vector_type(4)));

#define MFMA16(a, b, c) __builtin_amdgcn_mfma_f32_16x16x32_bf16((a), (b), (c), 0, 0, 0)

__device__ __forceinline__ short f2b(float f) {   // fp32->bf16, round-half-up
    union { float f; unsigned u; } v; v.f = f;
    return (short)((v.u + 0x8000u) >> 16);
}

// native RoPE sincos via revolutions + fract (no library range reduction)
__device__ __forceinline__ void rope_cs(int n, float f_rev, float* c, float* s) {
    float rev = (float)n * f_rev;
    float t = rev - floorf(rev);
    float ang = t * 6.283185307179586f;
    *c = __cosf(ang);
    *s = __sinf(ang);
}

#define L2_1E4_D32 0.4152410118609203f   // log2(10000)/32
#define INV2PI     0.15915494309189535f
#define QSCALE     0.18033688011112042f  // 0.125 * log2(e)

// ---------------------------------------------------------------------------
// Kernel 0: fused fp32 -> bf16 convert for x | Wq | Wk | Wv | Wo into ws base.
// ---------------------------------------------------------------------------
__global__ __launch_bounds__(256) void cvt_all_kernel(
    const float* __restrict__ x,  const float* __restrict__ wq,
    const float* __restrict__ wk, const float* __restrict__ wv,
    const float* __restrict__ wo, short* __restrict__ dst)
{
    int i = blockIdx.x * 256 + threadIdx.x;            // < 1 Mi
    const float* src; int off;
    if (i < (1 << 19)) { src = x; off = i; }
    else {
        int j = i - (1 << 19);
        int wsel = j >> 17;
        off = j & ((1 << 17) - 1);
        src = (wsel == 0) ? wq : (wsel == 1) ? wk : (wsel == 2) ? wv : wo;
    }
    const float4* s4 = (const float4*)src;
    float4 a = s4[2 * off], b = s4[2 * off + 1];
    v8s p;
    p[0] = f2b(a.x); p[1] = f2b(a.y); p[2] = f2b(a.z); p[3] = f2b(a.w);
    p[4] = f2b(b.x); p[5] = f2b(b.y); p[6] = f2b(b.z); p[7] = f2b(b.w);
    *(v8s*)&dst[8 * i] = p;
}

// ---------------------------------------------------------------------------
// Kernel 1: Q/K/V projections, 128x128 MFMA tile. Native-sincos RoPE.
//   z=0: K = RoPE(x @ Wk^T)        -> [bh][key][d]
//   z=1: V = x @ Wv^T (transposed) -> Vt[bh][d][key]
//   z=2: Q = QSCALE*RoPE(x @ Wq^T) -> Qb[bh][row][d]
// grid = (MTOT/128, DM/128, 3) = 768 blocks, 3/CU.
// ---------------------------------------------------------------------------
__global__ __launch_bounds__(256, 3) void qkv_rope_mfma(
    const short* __restrict__ xb, const short* __restrict__ Wqb,
    const short* __restrict__ Wkb, const short* __restrict__ Wvb,
    short* __restrict__ K, short* __restrict__ Vt, short* __restrict__ Qb)
{
    const int zz = blockIdx.z;
    const short* __restrict__ Wb = (zz == 0) ? Wkb : (zz == 1) ? Wvb : Wqb;
    const int m0 = blockIdx.x * 128, e00 = blockIdx.y * 128;
    const int tid = threadIdx.x;
    const int w = tid >> 6, lane = tid & 63, lq = lane >> 4, lr = lane & 15;
    const int wm = w >> 1, wn = w & 1;

    __shared__ union {
        struct { short As[128][32]; short Bs[128][32]; } p1;  // 16 KB
        short Css[128][136];                                   // 34 KB
    } u;

    v4f acc[4][4];
    #pragma unroll
    for (int i = 0; i < 4; ++i)
        for (int j = 0; j < 4; ++j)
            for (int r = 0; r < 4; ++r) acc[i][j][r] = 0.f;

    const int arow = tid >> 1, aseg = (tid & 1) * 16;
    for (int k0 = 0; k0 < DM; k0 += 32) {
        v8s a0 = *(const v8s*)&xb[(size_t)(m0 + arow) * DM + k0 + aseg];
        v8s a1 = *(const v8s*)&xb[(size_t)(m0 + arow) * DM + k0 + aseg + 8];
        v8s b0 = *(const v8s*)&Wb[(size_t)(e00 + arow) * DM + k0 + aseg];
        v8s b1 = *(const v8s*)&Wb[(size_t)(e00 + arow) * DM + k0 + aseg + 8];
        __syncthreads();
        *(v8s*)&u.p1.As[arow][aseg] = a0;
        *(v8s*)&u.p1.As[arow][aseg + 8] = a1;
        *(v8s*)&u.p1.Bs[arow][aseg] = b0;
        *(v8s*)&u.p1.Bs[arow][aseg + 8] = b1;
        __syncthreads();
        v8s af[4], bf[4];
        #pragma unroll
        for (int i = 0; i < 4; ++i)
            af[i] = *(const v8s*)&u.p1.As[64 * wm + 16 * i + lr][8 * lq];
        #pragma unroll
        for (int j = 0; j < 4; ++j)
            bf[j] = *(const v8s*)&u.p1.Bs[64 * wn + 16 * j + lr][8 * lq];
        #pragma unroll
        for (int i = 0; i < 4; ++i)
            #pragma unroll
            for (int j = 0; j < 4; ++j)
                acc[i][j] = MFMA16(af[i], bf[j], acc[i][j]);
    }
    __syncthreads();   // k-loop LDS reads done before Css overwrite

    const int b = m0 >> 11, n00 = m0 & (SEQ - 1);

    if (zz != 1) {
        // RoPE in-register (cols of this wave = one head; pairs nt <-> nt^2)
        short* __restrict__ dst = (zz == 0) ? K : Qb;
        const float sc = (zz == 0) ? 1.0f : QSCALE;
        float f0 = exp2f(-(float)lr * L2_1E4_D32) * INV2PI;
        float f1 = exp2f(-(float)(16 + lr) * L2_1E4_D32) * INV2PI;
        #pragma unroll
        for (int i = 0; i < 4; ++i) {
            #pragma unroll
            for (int r = 0; r < 4; ++r) {
                int row = 64 * wm + 16 * i + 4 * lq + r;
                int n = n00 + row;
                float c0v, s0v, c1v, s1v;
                rope_cs(n, f0, &c0v, &s0v);
                rope_cs(n, f1, &c1v, &s1v);
                float q0 = acc[i][0][r], q1 = acc[i][1][r];
                float q2 = acc[i][2][r], q3 = acc[i][3][r];
                u.Css[row][64 * wn + lr]      = f2b(sc * (q0 * c0v - q2 * s0v));
                u.Css[row][64 * wn + 16 + lr] = f2b(sc * (q1 * c1v - q3 * s1v));
                u.Css[row][64 * wn + 32 + lr] = f2b(sc * (q2 * c0v + q0 * s0v));
                u.Css[row][64 * wn + 48 + lr] = f2b(sc * (q3 * c1v + q1 * s1v));
            }
        }
        __syncthreads();
        int row = tid >> 1, hh = tid & 1;
        int h = (e00 >> 6) + hh;
        int n = n00 + row;
        size_t base = (((size_t)(b * NH + h)) * SEQ + n) * HD;
        #pragma unroll
        for (int p = 0; p < 8; ++p)
            *(v8s*)&dst[base + 8 * p] = *(const v8s*)&u.Css[row][64 * hh + 8 * p];
    } else {
        // V transposed: Css_T[col][row], packed b64 along row (r contiguous)
        #pragma unroll
        for (int i = 0; i < 4; ++i) {
            #pragma unroll
            for (int j = 0; j < 4; ++j) {
                v4s t;
                #pragma unroll
                for (int r = 0; r < 4; ++r) t[r] = f2b(acc[i][j][r]);
                *(v4s*)&u.Css[64 * wn + 16 * j + lr][64 * wm + 16 * i + 4 * lq] = t;
            }
        }
        __syncthreads();
        int c = tid >> 1, half = (tid & 1) * 64;
        int h = (e00 + c) >> 6, d = (e00 + c) & 63;
        size_t base = (((size_t)(b * NH + h)) * HD + d) * SEQ + n00 + half;
        #pragma unroll
        for (int p = 0; p < 8; ++p)
            *(v8s*)&Vt[base + 8 * p] = *(const v8s*)&u.Css[c][half + 8 * p];
    }
}

// ---------------------------------------------------------------------------
// Kernel 2: flash attention only (Q precomputed). 128-row Q-tile, 512 thr /
// 8 waves (one 16-row strip each). KCHUNK=128: one barrier pair per 128 keys.
// Fixed-max softmax (M=24 in mask bias), key-permuted K staging (packed v4s
// P-writes), K/V fragments hoisted, register prefetch.
// grid = (MTOT/128, NH) = 512 blocks, 2/CU.
// ---------------------------------------------------------------------------
__global__ __launch_bounds__(512, 4) void attn_mfma(
    const short* __restrict__ Qb, const short* __restrict__ K,
    const short* __restrict__ Vt, const int* __restrict__ mask,
    short* __restrict__ O)
{
    const int m0 = blockIdx.x * 128, h = blockIdx.y;
    const int b = m0 >> 11, n0 = m0 & (SEQ - 1), bh = b * NH + h;
    const int tid = threadIdx.x;
    const int w = tid >> 6, lane = tid & 63, lq = lane >> 4, lr = lane & 15;

    __shared__ short Ks[128][72];    // 18.4 KB (key-permuted within halves)
    __shared__ short Vs[64][136];    // 17.4 KB ([d][128 keys])
    __shared__ short Ps[128][72];    // 18.4 KB (wave-private 16-row strips)
    __shared__ float mbias[128];

    // ---- load Q A-fragments (rows 16w+lr, pre-scaled + RoPE'd) ----
    const short* __restrict__ Qh = Qb + (size_t)bh * SEQ * HD;
    v8s aq[2];
    #pragma unroll
    for (int ks = 0; ks < 2; ++ks)
        aq[ks] = *(const v8s*)&Qh[(size_t)(n0 + 16 * w + lr) * HD + 32 * ks + 8 * lq];

    float lacc[4] = {0.f, 0.f, 0.f, 0.f};
    v4f o[4];
    #pragma unroll
    for (int nt = 0; nt < 4; ++nt)
        for (int r = 0; r < 4; ++r) o[nt][r] = 0.f;

    // staging indices: K 128 rows x 64 d ; V 64 d x 128 keys
    const int kr = tid >> 2, kc = (tid & 3) * 16;
    const int krh = kr & 63;
    const int pkr = 64 * (kr >> 6) + 16 * (krh & 3) + (krh >> 2);  // permuted
    const int vr = tid >> 3, vc = (tid & 7) * 16;
    const short* __restrict__ Kb = K + (size_t)bh * SEQ * HD;
    const short* __restrict__ Vb = Vt + (size_t)bh * HD * SEQ;

    // prefetch chunk 0
    v8s k1 = *(const v8s*)&Kb[(size_t)kr * HD + kc];
    v8s k2 = *(const v8s*)&Kb[(size_t)kr * HD + kc + 8];
    v8s v1 = *(const v8s*)&Vb[(size_t)vr * SEQ + vc];
    v8s v2 = *(const v8s*)&Vb[(size_t)vr * SEQ + vc + 8];
    int mnext = (tid < 128) ? mask[b * SEQ + tid] : 0;

    for (int c0 = 0; c0 < SEQ; c0 += 128) {
        __syncthreads();                      // prev chunk LDS reads done
        *(v8s*)&Ks[pkr][kc] = k1;
        *(v8s*)&Ks[pkr][kc + 8] = k2;
        *(v8s*)&Vs[vr][vc] = v1;
        *(v8s*)&Vs[vr][vc + 8] = v2;
        if (tid < 128) mbias[tid] = mnext ? -24.0f : -1e30f;
        __syncthreads();
        if (c0 + 128 < SEQ) {                 // prefetch next chunk
            k1 = *(const v8s*)&Kb[(size_t)(c0 + 128 + kr) * HD + kc];
            k2 = *(const v8s*)&Kb[(size_t)(c0 + 128 + kr) * HD + kc + 8];
            v1 = *(const v8s*)&Vb[(size_t)vr * SEQ + c0 + 128 + vc];
            v2 = *(const v8s*)&Vb[(size_t)vr * SEQ + c0 + 128 + vc + 8];
            if (tid < 128) mnext = mask[b * SEQ + c0 + 128 + tid];
        }

        #pragma unroll
        for (int half = 0; half < 2; ++half) {
            // hoist K fragments; S col (nt,lr) <-> key 64*half + 4*lr + nt
            v8s kf[2][4];
            #pragma unroll
            for (int ks = 0; ks < 2; ++ks)
                #pragma unroll
                for (int nt = 0; nt < 4; ++nt)
                    kf[ks][nt] = *(const v8s*)&Ks[64 * half + 16 * nt + lr][32 * ks + 8 * lq];
            float bias[4];
            #pragma unroll
            for (int nt = 0; nt < 4; ++nt) bias[nt] = mbias[64 * half + 4 * lr + nt];

            v4f sv[4];
            #pragma unroll
            for (int nt = 0; nt < 4; ++nt)
                for (int r = 0; r < 4; ++r) sv[nt][r] = 0.f;
            #pragma unroll
            for (int ks = 0; ks < 2; ++ks)
                #pragma unroll
                for (int nt = 0; nt < 4; ++nt)
                    sv[nt] = MFMA16(aq[ks], kf[ks][nt], sv[nt]);

            // p = exp2(s + bias); packed v4s write (keys 4lr..4lr+3 of half)
            #pragma unroll
            for (int r = 0; r < 4; ++r) {
                v4s pk;
                #pragma unroll
                for (int nt = 0; nt < 4; ++nt) {
                    float p = exp2f(sv[nt][r] + bias[nt]);
                    lacc[r] += p;
                    pk[nt] = f2b(p);
                }
                *(v4s*)&Ps[16 * w + 4 * lq + r][4 * lr] = pk;
            }
            // O += P @ V_half  (Ps strip wave-private; V cols 64*half+...)
            #pragma unroll
            for (int ks = 0; ks < 2; ++ks) {
                v8s a = *(const v8s*)&Ps[16 * w + lr][32 * ks + 8 * lq];
                #pragma unroll
                for (int nt = 0; nt < 4; ++nt) {
                    v8s vf = *(const v8s*)&Vs[16 * nt + lr][64 * half + 32 * ks + 8 * lq];
                    o[nt] = MFMA16(a, vf, o[nt]);
                }
            }
        }
    }

    // ---- finalize: one butterfly per row; all-masked rows -> l=0 -> 0 ----
    #pragma unroll
    for (int r = 0; r < 4; ++r) {
        float l = lacc[r];
        l += __shfl_xor(l, 1);
        l += __shfl_xor(l, 2);
        l += __shfl_xor(l, 4);
        l += __shfl_xor(l, 8);
        float inv = (l > 0.f) ? 1.f / l : 0.f;
        int qrow = 16 * w + 4 * lq + r;
        #pragma unroll
        for (int nt = 0; nt < 4; ++nt)
            O[(size_t)(m0 + qrow) * DM + h * HD + 16 * nt + lr] =
                f2b(o[nt][r] * inv);
    }
}

// ---------------------------------------------------------------------------
// Kernel 3: out = O @ Wo^T, 64x128 MFMA tile (512 blocks), fp32 store.
// grid = (MTOT/64, DM/128).
// ---------------------------------------------------------------------------
__global__ __launch_bounds__(256, 2) void oproj_mfma(
    const short* __restrict__ O, const short* __restrict__ Wob,
    float* __restrict__ out)
{
    const int m0 = blockIdx.x * 64, e00 = blockIdx.y * 128;
    const int tid = threadIdx.x;
    const int w = tid >> 6, lane = tid & 63, lq = lane >> 4, lr = lane & 15;

    __shared__ short As[64][32];    // 4 KB
    __shared__ short Bs[128][32];   // 8 KB

    v4f acc[4][2];
    #pragma unroll
    for (int i = 0; i < 4; ++i)
        for (int j = 0; j < 2; ++j)
            for (int r = 0; r < 4; ++r) acc[i][j][r] = 0.f;

    const int arow = tid >> 2, aseg = (tid & 3) * 8;
    const int brow = tid >> 1, bseg = (tid & 1) * 16;
    for (int k0 = 0; k0 < DM; k0 += 32) {
        v8s a0 = *(const v8s*)&O[(size_t)(m0 + arow) * DM + k0 + aseg];
        v8s b0 = *(const v8s*)&Wob[(size_t)(e00 + brow) * DM + k0 + bseg];
        v8s b1 = *(const v8s*)&Wob[(size_t)(e00 + brow) * DM + k0 + bseg + 8];
        __syncthreads();
        *(v8s*)&As[arow][aseg] = a0;
        *(v8s*)&Bs[brow][bseg] = b0;
        *(v8s*)&Bs[brow][bseg + 8] = b1;
        __syncthreads();
        v8s af[4], bf[2];
        #pragma unroll
        for (int i = 0; i < 4; ++i)
            af[i] = *(const v8s*)&As[16 * i + lr][8 * lq];
        #pragma unroll
        for (int j = 0; j < 2; ++j)
            bf[j] = *(const v8s*)&Bs[32 * w + 16 * j + lr][8 * lq];
        #pragma unroll
        for (int i = 0; i < 4; ++i)
            #pragma unroll
            for (int j = 0; j < 2; ++j)
                acc[i][j] = MFMA16(af[i], bf[j], acc[i][j]);
    }

    #pragma unroll
    for (int i = 0; i < 4; ++i)
        #pragma unroll
        for (int r = 0; r < 4; ++r) {
            int m = m0 + 16 * i + 4 * lq + r;
            #pragma unroll
            for (int j = 0; j < 2; ++j)
                out[(size_t)m * DM + e00 + 32 * w + 16 * j + lr] = acc[i][j][r];
        }
}

// ---------------------------------------------------------------------------
extern "C" void kernel_launch(void* const* d_in, const int* in_sizes, int n_in,
                              void* d_out, int out_size, void* d_ws, size_t ws_size,
                              hipStream_t stream)
{
    const float* x    = (const float*)d_in[0];
    const int*   mask = (const int*)d_in[1];
    const float* Wq   = (const float*)d_in[2];
    const float* Wk   = (const float*)d_in[3];
    const float* Wv   = (const float*)d_in[4];
    const float* Wo   = (const float*)d_in[5];
    float* out = (float*)d_out;

    // ws (24 MiB of shorts): xb | Wqb | Wkb | Wvb | Wob | Qb
    //   xb region is reused for O after qkv_rope (attn no longer reads x).
    short* xb  = (short*)d_ws;                    // 8 MB (x, then O)
    short* Wqb = xb  + (size_t)MTOT * DM;         // 2 MB each
    short* Wkb = Wqb + (size_t)DM * DM;
    short* Wvb = Wkb + (size_t)DM * DM;
    short* Wob = Wvb + (size_t)DM * DM;
    short* Qb  = Wob + (size_t)DM * DM;           // 8 MB
    short* O   = xb;                              // alias (post-qkv)
    // d_out (16 MiB) doubles as K/Vt scratch until the final projection
    short* K  = (short*)d_out;                    // 8 MB
    short* Vt = K + (size_t)MTOT * DM;            // 8 MB

    cvt_all_kernel<<<4096, 256, 0, stream>>>(x, Wq, Wk, Wv, Wo, xb);

    dim3 g1(MTOT / 128, DM / 128, 3);
    qkv_rope_mfma<<<g1, 256, 0, stream>>>(xb, Wqb, Wkb, Wvb, K, Vt, Qb);

    dim3 g2(MTOT / 128, NH);
    attn_mfma<<<g2, 512, 0, stream>>>(Qb, K, Vt, mask, O);

    dim3 g3(MTOT / 64, DM / 128);
    oproj_mfma<<<g3, 256, 0, stream>>>(O, Wob, out);
}